// Round 10
// baseline (415.255 us; speedup 1.0000x reference)
//
#include <hip/hip_runtime.h>

#define IDTF 199.0f
#define DTF  (1.0f/199.0f)

typedef float f4 __attribute__((ext_vector_type(4)));

// ===================== PCR coefficient precompute (fp64) =====================
// (unchanged from round 9)
__global__ void k_pcr(float* __restrict__ C) {
    const double cc = 65025.0 / 199.0;   // eps*dt/dx^2 = 255^2/199
    __shared__ double a[2][256], b[2][256], c[2][256];
    __shared__ double AL[8][256], BE[8][256];
    const int x = threadIdx.x;
    double invd = 1.0;
    for (int mm = 0; mm < 2; mm++) {
        const int m = 1 - mm;
        double ai, bi, ci;
        if (m == 0) {
            ai = (x == 0) ? 0.0 : -cc;
            bi = 1.0 + 2.0 * cc;
            ci = (x == 255) ? 0.0 : -cc;
        } else {
            if (x == 0 || x == 255) { ai = 0.0; bi = 1.0; ci = 0.0; }
            else {
                ai = (x == 1) ? 0.0 : -cc;
                bi = 1.0 + 2.0 * cc;
                ci = (x == 254) ? 0.0 : -cc;
            }
        }
        int cur = 0;
        a[0][x] = ai; b[0][x] = bi; c[0][x] = ci;
        __syncthreads();
        for (int l = 0; l < 8; l++) {
            int s = 1 << l;
            int xm = (x - s < 0) ? 0 : x - s;
            int xp = (x + s > 255) ? 255 : x + s;
            double al = a[cur][x] / b[cur][xm];
            double be = c[cur][x] / b[cur][xp];
            AL[l][x] = al; BE[l][x] = be;
            double an = -al * a[cur][xm];
            double cn = -be * c[cur][xp];
            double bn = b[cur][x] - al * c[cur][xm] - be * a[cur][xp];
            a[1 - cur][x] = an; b[1 - cur][x] = bn; c[1 - cur][x] = cn;
            __syncthreads();
            cur ^= 1;
        }
        invd = 1.0 / b[cur][x];
        __syncthreads();
        float* Cr = C + (size_t)m * 22 * 256;
#pragma unroll
        for (int p = 0; p < 4; p++) {
            int s = 1 << (2 * p), s2 = 2 * s;
            double a0 = AL[2*p][x],   b0 = BE[2*p][x];
            double a1 = AL[2*p+1][x], b1 = BE[2*p+1][x];
            double am = (x - s2 >= 0) ? AL[2*p][x - s2] : 0.0;
            double bm = (x - s2 >= 0) ? BE[2*p][x - s2] : 0.0;
            double ap = (x + s2 < 256) ? AL[2*p][x + s2] : 0.0;
            double bq = (x + s2 < 256) ? BE[2*p][x + s2] : 0.0;
            double A3 = -a1 * am;
            double A2 = a1;
            double A1 = a0 - a1 * bm;
            double B1 = b0 - b1 * ap;
            double B2 = b1;
            double B3 = -b1 * bq;
            if (p < 3) {
                Cr[(p*6+0)*256 + x] = (float)A3;
                Cr[(p*6+1)*256 + x] = (float)A2;
                Cr[(p*6+2)*256 + x] = (float)A1;
                Cr[(p*6+3)*256 + x] = (float)B1;
                Cr[(p*6+4)*256 + x] = (float)B2;
                Cr[(p*6+5)*256 + x] = (float)B3;
            } else {
                Cr[18*256 + x] = (float)(A1 + B3);
                Cr[19*256 + x] = (float)(A2 + B2);
                Cr[20*256 + x] = (float)(A3 + B1);
            }
        }
        Cr[21*256 + x] = (float)invd;
        __syncthreads();
    }
    {
        int cur = 0;
        a[0][x] = (x == 0) ? -cc : 0.0;
        b[0][x] = (x == 255) ? -cc : 0.0;
        __syncthreads();
        for (int l = 0; l < 8; l++) {
            int s = 1 << l;
            int xm = (x - s < 0) ? 0 : x - s;
            int xp = (x + s > 255) ? 255 : x + s;
            double n1 = a[cur][x] - AL[l][x] * a[cur][xm] - BE[l][x] * a[cur][xp];
            double n2 = b[cur][x] - AL[l][x] * b[cur][xm] - BE[l][x] * b[cur][xp];
            a[1 - cur][x] = n1; b[1 - cur][x] = n2;
            __syncthreads();
            cur ^= 1;
        }
        double t1 = a[cur][x] * invd;
        double t2 = b[cur][x] * invd;
        c[0][x] = t1; c[1][x] = t2;
        __syncthreads();
        double K00 = 1.0 + c[0][254], K01 = c[1][254];
        double K10 = c[0][1],         K11 = 1.0 + c[1][1];
        double idet = 1.0 / (K00 * K11 - K01 * K10);
        double Ki00 = K11 * idet, Ki01 = -K01 * idet;
        double Ki10 = -K10 * idet, Ki11 = K00 * idet;
        C[44 * 256 + x] = (float)(t1 * Ki00 + t2 * Ki10);
        C[45 * 256 + x] = (float)(t1 * Ki01 + t2 * Ki11);
    }
}

// ===================== paired-scan split kernel =====================
// grid(256) = 128 batches x 2 roles (XCD-paired). 256 thr = 4 waves, each
// wave runs up to TWO independent scans (interleaved DS stages -> latency
// hiding), one matrix per wave (w0 = ic/Dirichlet + writer duty).
// role0: w0={ic}+wr(ch8-11); w1={f2,n8}; w2={f4,n9}; w3={n10,n11}
// role1: w0={ic}+wr(ch0-3); w1={f2+dW,n4}; w2={n3,n5}; w3={n6,n7}+wr(ch4-7)
// Timeline: early slots t=j (ic,f2,f4,n4); late slots t=j-1; writers t=j-2.
// Ring: [4][8][64] f4; per-step __syncthreads.
__global__ __launch_bounds__(256, 1) void k_split(const float* __restrict__ W,
        const float* __restrict__ U0, const float* __restrict__ C,
        float* __restrict__ out) {
    const int bid = blockIdx.x;
    const int role = (bid >> 3) & 1;
    const int b = (bid & 7) | ((bid >> 4) << 3);
    const int tid = threadIdx.x;
    const int wv = tid >> 6;
    const int L = tid & 63;

    // slot0: TY 0=ic, 1=prod dW, 2=prod dW^2, 3=late consumer
    static const signed char S0TY[2][4] = {{0,1,2,3},{0,1,3,3}};
    static const signed char S0FM[2][4] = {{0,0,0,3},{0,0,0,3}};
    static const signed char S0PA[2][4] = {{0,0,0,0},{0,0,0,1}};
    static const signed char S0PU[2][4] = {{0,1,2,5},{0,1,4,6}};
    // slot1: PR=present; TY 2=prod dW^2(early), 3=late
    static const signed char S1PR[2][4] = {{0,1,1,1},{0,1,1,1}};
    static const signed char S1TY[2][4] = {{3,3,3,3},{3,2,3,3}};
    static const signed char S1FM[2][4] = {{0,4,1,2},{0,0,1,2}};
    static const signed char S1PA[2][4] = {{0,1,1,2},{0,0,0,1}};
    static const signed char S1PB[2][4] = {{0,0,0,1},{0,0,0,0}};
    static const signed char S1PU[2][4] = {{-1,3,4,6},{-1,3,5,7}};
    static const signed char NWT[2][4]  = {{0,1,1,0},{0,1,1,0}};
    static const signed char WGT[2][4]  = {{2,-1,-1,-1},{0,-1,-1,1}};
    static const signed char WPT[2][4][4] = {
        {{3,4,5,6},{0,0,0,0},{0,0,0,0},{0,0,0,0}},
        {{2,0,1,4},{0,0,0,0},{0,0,0,0},{3,5,6,7}}};

    const int s0ty = S0TY[role][wv], s0fm = S0FM[role][wv];
    const int s0pa = S0PA[role][wv], s0pu = S0PU[role][wv];
    const bool s1pr = S1PR[role][wv];
    const int s1ty = S1TY[role][wv], s1fm = S1FM[role][wv];
    const int s1pa = S1PA[role][wv], s1pb = S1PB[role][wv];
    const int s1pu = S1PU[role][wv];
    const bool needW = NWT[role][wv];
    const int wgrp = WGT[role][wv];
    const int wpl0 = WPT[role][wv][0], wpl1 = WPT[role][wv][1];
    const int wpl2 = WPT[role][wv][2], wpl3 = WPT[role][wv][3];
    const bool pubDW = (role == 1 && wv == 1);
    const bool wood0 = (wv != 0);      // ic (w0 slot0) skips Woodbury
    const int mat = (wv == 0) ? 1 : 0; // w0 = Dirichlet, others periodic

    // ---- coefficients (one set per wave; negated for fmaf) ----
    const float* Cm = C + (size_t)mat * 22 * 256;
    float ncf[21][4], ivd4[4], npk0[4], npk1[4];
#pragma unroll
    for (int r = 0; r < 21; r++) {
        f4 v = *(const f4*)&Cm[r * 256 + 4 * L];
#pragma unroll
        for (int q = 0; q < 4; q++) ncf[r][q] = -v[q];
    }
    {
        f4 vd = *(const f4*)&Cm[21 * 256 + 4 * L];
        f4 p0 = *(const f4*)&C[44 * 256 + 4 * L];
        f4 p1 = *(const f4*)&C[45 * 256 + 4 * L];
#pragma unroll
        for (int q = 0; q < 4; q++) { ivd4[q] = vd[q]; npk0[q] = -p0[q]; npk1[q] = -p1[q]; }
    }

    __shared__ f4 ring[4][8][64];   // 32 KB
    __shared__ f4 scr[4][2][64];    // 8 KB: [wave][slot][lane]

    // ---- state init ----
    float y0[4] = {0.f,0.f,0.f,0.f}, y1[4] = {0.f,0.f,0.f,0.f};
    if (s0ty == 0) {
        f4 u0 = *(const f4*)&U0[b * 256 + 4 * L];
#pragma unroll
        for (int q = 0; q < 4; q++) y0[q] = u0[q];
    }
    if (wgrp >= 0) {   // t=0 output row
        f4* of4 = (f4*)out;
        size_t rb = (size_t)b * 200 * 768;
#pragma unroll
        for (int q = 0; q < 4; q++) {
            int x = 4 * L + q;
            f4 v = {0.f, 0.f, 0.f, 0.f};
            if (wgrp == 0) v[1] = U0[b * 256 + x];
            of4[rb + (size_t)x * 3 + wgrp] = v;
        }
    }
    float wprev[4] = {0,0,0,0}, wcur[4] = {0,0,0,0}, wnxt[4] = {0,0,0,0};
    float dwv[4] = {0,0,0,0}, dwold[4] = {0,0,0,0};
    if (needW) {
        f4 w0 = *(const f4*)&W[((size_t)b * 200 + 0) * 256 + 4 * L];
        f4 w1 = *(const f4*)&W[((size_t)b * 200 + 1) * 256 + 4 * L];
#pragma unroll
        for (int q = 0; q < 4; q++) { wprev[q] = w0[q]; wcur[q] = w1[q]; }
    }
    __syncthreads();

    for (int j = 1; j <= 201; j++) {
        const bool e_ok = (j <= 199);
        const bool l_ok = (j >= 2 && j <= 200);
        const bool a0 = (s0ty == 3) ? l_ok : e_ok;
        const bool a1 = s1pr && ((s1ty == 3) ? l_ok : e_ok);
        if (needW) {
            if (j >= 2) {
#pragma unroll
                for (int q = 0; q < 4; q++) dwold[q] = dwv[q];
            }
            if (j <= 199) {
#pragma unroll
                for (int q = 0; q < 4; q++) dwv[q] = (wcur[q] - wprev[q]) * IDTF;
                if (j <= 198) {
                    f4 wn = *(const f4*)&W[((size_t)b * 200 + j + 1) * 256 + 4 * L];
#pragma unroll
                    for (int q = 0; q < 4; q++) wnxt[q] = wn[q];
                }
            }
        }
        float d0[4], d1[4];
        // ---- forcing slot0 ----
        if (a0) {
            if (s0ty == 0) {
#pragma unroll
                for (int q = 0; q < 4; q++) d0[q] = y0[q];
            } else if (s0ty == 1) {
#pragma unroll
                for (int q = 0; q < 4; q++) d0[q] = fmaf(dwv[q], DTF, y0[q]);
            } else if (s0ty == 2) {
#pragma unroll
                for (int q = 0; q < 4; q++) d0[q] = fmaf(dwv[q] * dwv[q], DTF, y0[q]);
            } else {
                f4 u = ring[(j - 1) & 3][s0pa][L];
#pragma unroll
                for (int q = 0; q < 4; q++) {
                    float fq = (s0fm == 0) ? u[q] : ((s0fm == 1) ? dwold[q] * u[q] : u[q] * u[q]);
                    d0[q] = fmaf(fq, DTF, y0[q]);
                }
            }
        }
        // ---- forcing slot1 ----
        if (a1) {
            if (s1ty == 2) {
#pragma unroll
                for (int q = 0; q < 4; q++) d1[q] = fmaf(dwv[q] * dwv[q], DTF, y1[q]);
            } else {
                f4 u = ring[(j - 1) & 3][s1pa][L];
                f4 v = (s1fm == 2) ? ring[(j - 1) & 3][s1pb][L] : u;
#pragma unroll
                for (int q = 0; q < 4; q++) {
                    float fq;
                    if (s1fm == 1)      fq = dwold[q] * u[q];
                    else if (s1fm == 2) fq = v[q] * u[q];
                    else if (s1fm == 4) fq = u[q] * u[q] * u[q];
                    else                fq = u[q] * u[q];
                    d1[q] = fmaf(fq, DTF, y1[q]);
                }
            }
        }
        // ---- PCR solve, both slots interleaved ----
        if (a0 || a1) {
            {   // stage 0 (s=1,2)
                __builtin_amdgcn_wave_barrier();
                if (a0) { f4 pk; pk[0]=d0[0]; pk[1]=d0[1]; pk[2]=d0[2]; pk[3]=d0[3]; scr[wv][0][L] = pk; }
                if (a1) { f4 pk; pk[0]=d1[0]; pk[1]=d1[1]; pk[2]=d1[2]; pk[3]=d1[3]; scr[wv][1][L] = pk; }
                __builtin_amdgcn_wave_barrier();
                f4 vm0, vp0, vm1, vp1;
                if (a0) { vm0 = scr[wv][0][(L + 63) & 63]; vp0 = scr[wv][0][(L + 1) & 63]; }
                if (a1) { vm1 = scr[wv][1][(L + 63) & 63]; vp1 = scr[wv][1][(L + 1) & 63]; }
                if (a0) {
                    float w[12], r[4];
                    w[0]=vm0[0]; w[1]=vm0[1]; w[2]=vm0[2]; w[3]=vm0[3];
                    w[4]=d0[0];  w[5]=d0[1];  w[6]=d0[2];  w[7]=d0[3];
                    w[8]=vp0[0]; w[9]=vp0[1]; w[10]=vp0[2]; w[11]=vp0[3];
#pragma unroll
                    for (int q = 0; q < 4; q++) {
                        float t0 = fmaf(ncf[0][q], w[q+1], fmaf(ncf[1][q], w[q+2], w[4+q]));
                        float t1 = fmaf(ncf[2][q], w[q+3], fmaf(ncf[3][q], w[q+5], t0));
                        r[q] = fmaf(ncf[4][q], w[q+6], fmaf(ncf[5][q], w[q+7], t1));
                    }
                    d0[0]=r[0]; d0[1]=r[1]; d0[2]=r[2]; d0[3]=r[3];
                }
                if (a1) {
                    float w[12], r[4];
                    w[0]=vm1[0]; w[1]=vm1[1]; w[2]=vm1[2]; w[3]=vm1[3];
                    w[4]=d1[0];  w[5]=d1[1];  w[6]=d1[2];  w[7]=d1[3];
                    w[8]=vp1[0]; w[9]=vp1[1]; w[10]=vp1[2]; w[11]=vp1[3];
#pragma unroll
                    for (int q = 0; q < 4; q++) {
                        float t0 = fmaf(ncf[0][q], w[q+1], fmaf(ncf[1][q], w[q+2], w[4+q]));
                        float t1 = fmaf(ncf[2][q], w[q+3], fmaf(ncf[3][q], w[q+5], t0));
                        r[q] = fmaf(ncf[4][q], w[q+6], fmaf(ncf[5][q], w[q+7], t1));
                    }
                    d1[0]=r[0]; d1[1]=r[1]; d1[2]=r[2]; d1[3]=r[3];
                }
            }
#pragma unroll
            for (int st = 1; st < 3; st++) {   // stage1: s=4; stage2: s=16
                const int u = (st == 1) ? 1 : 4;
                __builtin_amdgcn_wave_barrier();
                if (a0) { f4 pk; pk[0]=d0[0]; pk[1]=d0[1]; pk[2]=d0[2]; pk[3]=d0[3]; scr[wv][0][L] = pk; }
                if (a1) { f4 pk; pk[0]=d1[0]; pk[1]=d1[1]; pk[2]=d1[2]; pk[3]=d1[3]; scr[wv][1][L] = pk; }
                __builtin_amdgcn_wave_barrier();
                f4 m10, m20, m30, q10, q20, q30;
                f4 m11, m21, m31, q11, q21, q31;
                if (a0) {
                    m10 = scr[wv][0][(L - u) & 63];   m20 = scr[wv][0][(L - 2*u) & 63];
                    m30 = scr[wv][0][(L - 3*u) & 63]; q10 = scr[wv][0][(L + u) & 63];
                    q20 = scr[wv][0][(L + 2*u) & 63]; q30 = scr[wv][0][(L + 3*u) & 63];
                }
                if (a1) {
                    m11 = scr[wv][1][(L - u) & 63];   m21 = scr[wv][1][(L - 2*u) & 63];
                    m31 = scr[wv][1][(L - 3*u) & 63]; q11 = scr[wv][1][(L + u) & 63];
                    q21 = scr[wv][1][(L + 2*u) & 63]; q31 = scr[wv][1][(L + 3*u) & 63];
                }
                const int r0 = st * 6;
                if (a0) {
#pragma unroll
                    for (int q = 0; q < 4; q++) {
                        float t0 = fmaf(ncf[r0+0][q], m30[q], fmaf(ncf[r0+1][q], m20[q], d0[q]));
                        float t1 = fmaf(ncf[r0+2][q], m10[q], fmaf(ncf[r0+3][q], q10[q], t0));
                        d0[q]   = fmaf(ncf[r0+4][q], q20[q], fmaf(ncf[r0+5][q], q30[q], t1));
                    }
                }
                if (a1) {
#pragma unroll
                    for (int q = 0; q < 4; q++) {
                        float t0 = fmaf(ncf[r0+0][q], m31[q], fmaf(ncf[r0+1][q], m21[q], d1[q]));
                        float t1 = fmaf(ncf[r0+2][q], m11[q], fmaf(ncf[r0+3][q], q11[q], t0));
                        d1[q]   = fmaf(ncf[r0+4][q], q21[q], fmaf(ncf[r0+5][q], q31[q], t1));
                    }
                }
            }
            {   // stage 3 (s=64,128)
                __builtin_amdgcn_wave_barrier();
                if (a0) { f4 pk; pk[0]=d0[0]; pk[1]=d0[1]; pk[2]=d0[2]; pk[3]=d0[3]; scr[wv][0][L] = pk; }
                if (a1) { f4 pk; pk[0]=d1[0]; pk[1]=d1[1]; pk[2]=d1[2]; pk[3]=d1[3]; scr[wv][1][L] = pk; }
                __builtin_amdgcn_wave_barrier();
                f4 vM0, vC0, vP0, vM1, vC1, vP1;
                if (a0) {
                    vM0 = scr[wv][0][(L + 48) & 63];
                    vC0 = scr[wv][0][(L + 32) & 63];
                    vP0 = scr[wv][0][(L + 16) & 63];
                }
                if (a1) {
                    vM1 = scr[wv][1][(L + 48) & 63];
                    vC1 = scr[wv][1][(L + 32) & 63];
                    vP1 = scr[wv][1][(L + 16) & 63];
                }
                if (a0) {
#pragma unroll
                    for (int q = 0; q < 4; q++)
                        d0[q] = fmaf(ncf[18][q], vM0[q], fmaf(ncf[19][q], vC0[q], fmaf(ncf[20][q], vP0[q], d0[q])));
                }
                if (a1) {
#pragma unroll
                    for (int q = 0; q < 4; q++)
                        d1[q] = fmaf(ncf[18][q], vM1[q], fmaf(ncf[19][q], vC1[q], fmaf(ncf[20][q], vP1[q], d1[q])));
                }
            }
            // ---- diagonal + Woodbury + state update + publish ----
            if (a0) {
#pragma unroll
                for (int q = 0; q < 4; q++) d0[q] *= ivd4[q];
                if (wood0) {
                    float s1 = __builtin_bit_cast(float,
                        __builtin_amdgcn_readlane(__builtin_bit_cast(int, d0[2]), 63));
                    float s2 = __builtin_bit_cast(float,
                        __builtin_amdgcn_readlane(__builtin_bit_cast(int, d0[1]), 0));
#pragma unroll
                    for (int q = 0; q < 4; q++)
                        d0[q] = fmaf(npk0[q], s1, fmaf(npk1[q], s2, d0[q]));
                }
#pragma unroll
                for (int q = 0; q < 4; q++) y0[q] = d0[q];
                const int t0i = (s0ty == 3) ? (j - 1) : j;
                f4 pk; pk[0]=y0[0]; pk[1]=y0[1]; pk[2]=y0[2]; pk[3]=y0[3];
                ring[t0i & 3][s0pu][L] = pk;
            }
            if (a1) {
#pragma unroll
                for (int q = 0; q < 4; q++) d1[q] *= ivd4[q];
                {
                    float s1 = __builtin_bit_cast(float,
                        __builtin_amdgcn_readlane(__builtin_bit_cast(int, d1[2]), 63));
                    float s2 = __builtin_bit_cast(float,
                        __builtin_amdgcn_readlane(__builtin_bit_cast(int, d1[1]), 0));
#pragma unroll
                    for (int q = 0; q < 4; q++)
                        d1[q] = fmaf(npk0[q], s1, fmaf(npk1[q], s2, d1[q]));
                }
#pragma unroll
                for (int q = 0; q < 4; q++) y1[q] = d1[q];
                const int t1i = (s1ty == 3) ? (j - 1) : j;
                f4 pk; pk[0]=y1[0]; pk[1]=y1[1]; pk[2]=y1[2]; pk[3]=y1[3];
                ring[t1i & 3][s1pu][L] = pk;
            }
        }
        if (pubDW && e_ok) {
            f4 pk; pk[0]=dwv[0]; pk[1]=dwv[1]; pk[2]=dwv[2]; pk[3]=dwv[3];
            ring[j & 3][2][L] = pk;
        }
        if (needW && j <= 198) {
#pragma unroll
            for (int q = 0; q < 4; q++) { wprev[q] = wcur[q]; wcur[q] = wnxt[q]; }
        }
        // ---- writer duty (lag 2) ----
        if (wgrp >= 0 && j >= 3) {
            const int tw = j - 2;
            const int s = tw & 3;
            f4 p0 = ring[s][wpl0][L];
            f4 p1 = ring[s][wpl1][L];
            f4 p2 = ring[s][wpl2][L];
            f4 p3 = ring[s][wpl3][L];
            f4* of4 = (f4*)out;
            size_t rb = ((size_t)b * 200 + tw) * 768;
#pragma unroll
            for (int q = 0; q < 4; q++) {
                f4 v; v[0] = p0[q]; v[1] = p1[q]; v[2] = p2[q]; v[3] = p3[q];
                of4[rb + (size_t)(4 * L + q) * 3 + wgrp] = v;
            }
        }
        __syncthreads();
    }
}

// ===================== launch =====================
extern "C" void kernel_launch(void* const* d_in, const int* in_sizes, int n_in,
                              void* d_out, int out_size, void* d_ws, size_t ws_size,
                              hipStream_t stream) {
    const float* W = (const float*)d_in[0];
    const float* U0 = (const float*)d_in[1];
    float* out = (float*)d_out;
    float* C = (float*)d_ws;   // 46*256 floats = 47 KB

    k_pcr<<<1, 256, 0, stream>>>(C);
    k_split<<<dim3(256), 256, 0, stream>>>(W, U0, C, out);
}

// Round 11
// 281.474 us; speedup vs baseline: 1.4753x; 1.4753x over previous
//
#include <hip/hip_runtime.h>

#define IDTF 199.0f
#define DTF  (1.0f/199.0f)

typedef float f4 __attribute__((ext_vector_type(4)));

// LDS-only barrier: orders DS ops across the workgroup WITHOUT draining the
// global (vmcnt) queue. __syncthreads() would insert s_waitcnt vmcnt(0) and
// stall every wave on outstanding global stores (~600-900 cyc) each step;
// the ring protocol only needs LDS ordering.
__device__ __forceinline__ void lds_barrier() {
    asm volatile("s_waitcnt lgkmcnt(0)\n\ts_barrier" ::: "memory");
}

// ===================== PCR coefficient precompute (fp64) =====================
// (unchanged from round 9)
__global__ void k_pcr(float* __restrict__ C) {
    const double cc = 65025.0 / 199.0;   // eps*dt/dx^2 = 255^2/199
    __shared__ double a[2][256], b[2][256], c[2][256];
    __shared__ double AL[8][256], BE[8][256];
    const int x = threadIdx.x;
    double invd = 1.0;
    for (int mm = 0; mm < 2; mm++) {
        const int m = 1 - mm;
        double ai, bi, ci;
        if (m == 0) {
            ai = (x == 0) ? 0.0 : -cc;
            bi = 1.0 + 2.0 * cc;
            ci = (x == 255) ? 0.0 : -cc;
        } else {
            if (x == 0 || x == 255) { ai = 0.0; bi = 1.0; ci = 0.0; }
            else {
                ai = (x == 1) ? 0.0 : -cc;
                bi = 1.0 + 2.0 * cc;
                ci = (x == 254) ? 0.0 : -cc;
            }
        }
        int cur = 0;
        a[0][x] = ai; b[0][x] = bi; c[0][x] = ci;
        __syncthreads();
        for (int l = 0; l < 8; l++) {
            int s = 1 << l;
            int xm = (x - s < 0) ? 0 : x - s;
            int xp = (x + s > 255) ? 255 : x + s;
            double al = a[cur][x] / b[cur][xm];
            double be = c[cur][x] / b[cur][xp];
            AL[l][x] = al; BE[l][x] = be;
            double an = -al * a[cur][xm];
            double cn = -be * c[cur][xp];
            double bn = b[cur][x] - al * c[cur][xm] - be * a[cur][xp];
            a[1 - cur][x] = an; b[1 - cur][x] = bn; c[1 - cur][x] = cn;
            __syncthreads();
            cur ^= 1;
        }
        invd = 1.0 / b[cur][x];
        __syncthreads();
        float* Cr = C + (size_t)m * 22 * 256;
#pragma unroll
        for (int p = 0; p < 4; p++) {
            int s = 1 << (2 * p), s2 = 2 * s;
            double a0 = AL[2*p][x],   b0 = BE[2*p][x];
            double a1 = AL[2*p+1][x], b1 = BE[2*p+1][x];
            double am = (x - s2 >= 0) ? AL[2*p][x - s2] : 0.0;
            double bm = (x - s2 >= 0) ? BE[2*p][x - s2] : 0.0;
            double ap = (x + s2 < 256) ? AL[2*p][x + s2] : 0.0;
            double bq = (x + s2 < 256) ? BE[2*p][x + s2] : 0.0;
            double A3 = -a1 * am;
            double A2 = a1;
            double A1 = a0 - a1 * bm;
            double B1 = b0 - b1 * ap;
            double B2 = b1;
            double B3 = -b1 * bq;
            if (p < 3) {
                Cr[(p*6+0)*256 + x] = (float)A3;
                Cr[(p*6+1)*256 + x] = (float)A2;
                Cr[(p*6+2)*256 + x] = (float)A1;
                Cr[(p*6+3)*256 + x] = (float)B1;
                Cr[(p*6+4)*256 + x] = (float)B2;
                Cr[(p*6+5)*256 + x] = (float)B3;
            } else {
                Cr[18*256 + x] = (float)(A1 + B3);
                Cr[19*256 + x] = (float)(A2 + B2);
                Cr[20*256 + x] = (float)(A3 + B1);
            }
        }
        Cr[21*256 + x] = (float)invd;
        __syncthreads();
    }
    {
        int cur = 0;
        a[0][x] = (x == 0) ? -cc : 0.0;
        b[0][x] = (x == 255) ? -cc : 0.0;
        __syncthreads();
        for (int l = 0; l < 8; l++) {
            int s = 1 << l;
            int xm = (x - s < 0) ? 0 : x - s;
            int xp = (x + s > 255) ? 255 : x + s;
            double n1 = a[cur][x] - AL[l][x] * a[cur][xm] - BE[l][x] * a[cur][xp];
            double n2 = b[cur][x] - AL[l][x] * b[cur][xm] - BE[l][x] * b[cur][xp];
            a[1 - cur][x] = n1; b[1 - cur][x] = n2;
            __syncthreads();
            cur ^= 1;
        }
        double t1 = a[cur][x] * invd;
        double t2 = b[cur][x] * invd;
        c[0][x] = t1; c[1][x] = t2;
        __syncthreads();
        double K00 = 1.0 + c[0][254], K01 = c[1][254];
        double K10 = c[0][1],         K11 = 1.0 + c[1][1];
        double idet = 1.0 / (K00 * K11 - K01 * K10);
        double Ki00 = K11 * idet, Ki01 = -K01 * idet;
        double Ki10 = -K10 * idet, Ki11 = K00 * idet;
        C[44 * 256 + x] = (float)(t1 * Ki00 + t2 * Ki10);
        C[45 * 256 + x] = (float)(t1 * Ki01 + t2 * Ki11);
    }
}

// ===================== split scan kernel (R9 structure + LDS-only barrier) ==
// grid(256) = 128 batches x 2 roles (paired 8 apart -> same XCD).
// 448 threads = 7 waves; lane L owns x = 4L..4L+3.
// role0 waves: {ic, f2, f4*, n8, n9, n10, n11}; writer wave n10 stores ch8-11.
// role1 waves: {ic*, f2*(+dW), n4, n3, n5, n6, n7}; writers n3 (ch0-3) and
// n6 (ch4-7). 4-slot LDS plane ring; writers lag 2 steps, float4 stores.
__global__ __launch_bounds__(448, 1) void k_split(const float* __restrict__ W,
        const float* __restrict__ U0, const float* __restrict__ C,
        float* __restrict__ out) {
    const int bid = blockIdx.x;
    const int role = (bid >> 3) & 1;
    const int b = (bid & 7) | ((bid >> 4) << 3);
    const int tid = threadIdx.x;
    const int wv = tid >> 6;
    const int L = tid & 63;

    // config tables [role][wv]
    static const signed char FMT[2][7] = {{-1,-1,-1, 4, 1, 3, 2},
                                          {-1,-1,-1, 0, 1, 3, 2}};
    static const signed char PAT[2][7] = {{ 0, 0, 0, 1, 1, 0, 2},
                                          { 0, 0, 0, 0, 0, 1, 1}};
    static const signed char PBT[2][7] = {{ 0, 0, 0, 0, 0, 0, 1},
                                          { 0, 0, 0, 0, 0, 0, 0}};
    static const signed char PUBT[2][7]= {{ 0, 1, 2, 3, 4, 5, 6},
                                          { 0, 1, 3, 4, 5, 6, 7}};
    static const signed char NWT[2][7] = {{ 0, 1, 1, 0, 1, 0, 0},
                                          { 0, 1, 1, 0, 1, 0, 0}};
    static const signed char WGT[2][7] = {{-1,-1,-1,-1,-1, 2,-1},
                                          {-1,-1,-1, 0,-1, 1,-1}};
    static const signed char WPT[2][7][4] = {
        {{0,0,0,0},{0,0,0,0},{0,0,0,0},{0,0,0,0},{0,0,0,0},{3,4,5,6},{0,0,0,0}},
        {{0,0,0,0},{0,0,0,0},{0,0,0,0},{2,0,1,4},{0,0,0,0},{3,5,6,7},{0,0,0,0}}};

    const bool isIC = (wv == 0);
    const bool isProd = (wv < 3);
    const int pmode = wv;                 // producers: 0=ic, 1=dW, 2=dW^2
    const int fmode = FMT[role][wv];
    const int pAi = PAT[role][wv], pBi = PBT[role][wv];
    const int pubP = PUBT[role][wv];
    const bool needW = NWT[role][wv];
    const int wgrp = WGT[role][wv];
    const int wpl0 = WPT[role][wv][0], wpl1 = WPT[role][wv][1];
    const int wpl2 = WPT[role][wv][2], wpl3 = WPT[role][wv][3];
    const bool pubDW = (role == 1 && wv == 1);
    const int mat = isIC ? 1 : 0;

    // ---- fused-stage coefficients into registers (negated for fmaf) ----
    const float* Cm = C + (size_t)mat * 22 * 256;
    float ncf[21][4], ivd4[4], npk0[4], npk1[4];
#pragma unroll
    for (int r = 0; r < 21; r++) {
        f4 v = *(const f4*)&Cm[r * 256 + 4 * L];
#pragma unroll
        for (int q = 0; q < 4; q++) ncf[r][q] = -v[q];
    }
    {
        f4 vd = *(const f4*)&Cm[21 * 256 + 4 * L];
        f4 p0 = *(const f4*)&C[44 * 256 + 4 * L];
        f4 p1 = *(const f4*)&C[45 * 256 + 4 * L];
#pragma unroll
        for (int q = 0; q < 4; q++) { ivd4[q] = vd[q]; npk0[q] = -p0[q]; npk1[q] = -p1[q]; }
    }

    __shared__ f4 ring[4][8][64];   // 32 KB: [slot][plane][lane]
    __shared__ f4 scr[7][64];       // 7 KB per-wave PCR exchange

    // ---- state init ----
    float y[4] = {0.f, 0.f, 0.f, 0.f};
    if (isIC) {
        f4 u0 = *(const f4*)&U0[b * 256 + 4 * L];
#pragma unroll
        for (int q = 0; q < 4; q++) y[q] = u0[q];
    }
    // t=0 output row (writer waves; float4 stores)
    if (wgrp >= 0) {
        f4* of4 = (f4*)out;
        size_t rb = (size_t)b * 200 * 768;
#pragma unroll
        for (int q = 0; q < 4; q++) {
            int x = 4 * L + q;
            f4 v = {0.f, 0.f, 0.f, 0.f};
            if (wgrp == 0) v[1] = U0[b * 256 + x];
            of4[rb + (size_t)x * 3 + wgrp] = v;
        }
    }
    float wprev[4] = {0,0,0,0}, wcur[4] = {0,0,0,0}, wnxt[4] = {0,0,0,0};
    if (needW) {
        f4 w0 = *(const f4*)&W[((size_t)b * 200 + 0) * 256 + 4 * L];
        f4 w1 = *(const f4*)&W[((size_t)b * 200 + 1) * 256 + 4 * L];
#pragma unroll
        for (int q = 0; q < 4; q++) { wprev[q] = w0[q]; wcur[q] = w1[q]; }
    }
    __syncthreads();

    // timeline: producers t=j (j<=199); consumers t=j-1 (2<=j<=200);
    // writers t=j-2 (3<=j<=201). Ring slot = t&3 (4 slots, lag<=2 safe).
    for (int j = 1; j <= 201; j++) {
        const int t = isProd ? j : (j - 1);
        const bool active = isProd ? (j <= 199) : (j >= 2 && j <= 200);
        if (active) {
            float dwv[4] = {0,0,0,0};
            if (needW) {
#pragma unroll
                for (int q = 0; q < 4; q++) dwv[q] = (wcur[q] - wprev[q]) * IDTF;
                if (t <= 198) {
                    f4 wn = *(const f4*)&W[((size_t)b * 200 + t + 1) * 256 + 4 * L];
#pragma unroll
                    for (int q = 0; q < 4; q++) wnxt[q] = wn[q];
                }
            }
            // ---- forcing ----
            float d[4];
            if (isProd) {
                if (pmode == 0) {
#pragma unroll
                    for (int q = 0; q < 4; q++) d[q] = y[q];
                } else if (pmode == 1) {
#pragma unroll
                    for (int q = 0; q < 4; q++) d[q] = fmaf(dwv[q], DTF, y[q]);
                } else {
#pragma unroll
                    for (int q = 0; q < 4; q++) d[q] = fmaf(dwv[q] * dwv[q], DTF, y[q]);
                }
            } else {
                f4 pa = ring[t & 3][pAi][L];
                f4 pb = (fmode == 2) ? ring[t & 3][pBi][L] : pa;
#pragma unroll
                for (int q = 0; q < 4; q++) {
                    float fq;
                    if (fmode == 0)      fq = pa[q];
                    else if (fmode == 1) fq = dwv[q] * pa[q];
                    else if (fmode == 2) fq = pb[q] * pa[q];
                    else if (fmode == 3) fq = pa[q] * pa[q];
                    else                 fq = pa[q] * pa[q] * pa[q];
                    d[q] = fmaf(fq, DTF, y[q]);
                }
            }
            // ---- PCR solve: 4 fused stages, per-wave LDS b128 exchanges ----
            {   // stage 0 (s=1,2): lanes +-1, 12-elem window
                __builtin_amdgcn_wave_barrier();
                f4 pk; pk[0] = d[0]; pk[1] = d[1]; pk[2] = d[2]; pk[3] = d[3];
                scr[wv][L] = pk;
                __builtin_amdgcn_wave_barrier();
                f4 vm = scr[wv][(L + 63) & 63];
                f4 vp = scr[wv][(L + 1) & 63];
                __builtin_amdgcn_wave_barrier();
                float w[12], r[4];
                w[0]=vm[0]; w[1]=vm[1]; w[2]=vm[2]; w[3]=vm[3];
                w[4]=d[0];  w[5]=d[1];  w[6]=d[2];  w[7]=d[3];
                w[8]=vp[0]; w[9]=vp[1]; w[10]=vp[2]; w[11]=vp[3];
#pragma unroll
                for (int q = 0; q < 4; q++) {
                    float t0 = fmaf(ncf[0][q], w[q + 1], fmaf(ncf[1][q], w[q + 2], w[4 + q]));
                    float t1 = fmaf(ncf[2][q], w[q + 3], fmaf(ncf[3][q], w[q + 5], t0));
                    r[q] = fmaf(ncf[4][q], w[q + 6], fmaf(ncf[5][q], w[q + 7], t1));
                }
                d[0] = r[0]; d[1] = r[1]; d[2] = r[2]; d[3] = r[3];
            }
#pragma unroll
            for (int st = 1; st < 3; st++) {   // stage1: s=4; stage2: s=16
                const int u = (st == 1) ? 1 : 4;
                __builtin_amdgcn_wave_barrier();
                f4 pk; pk[0] = d[0]; pk[1] = d[1]; pk[2] = d[2]; pk[3] = d[3];
                scr[wv][L] = pk;
                __builtin_amdgcn_wave_barrier();
                f4 m1 = scr[wv][(L - u) & 63];
                f4 m2 = scr[wv][(L - 2 * u) & 63];
                f4 m3 = scr[wv][(L - 3 * u) & 63];
                f4 q1 = scr[wv][(L + u) & 63];
                f4 q2 = scr[wv][(L + 2 * u) & 63];
                f4 q3 = scr[wv][(L + 3 * u) & 63];
                __builtin_amdgcn_wave_barrier();
                const int r0 = st * 6;
#pragma unroll
                for (int q = 0; q < 4; q++) {
                    float t0 = fmaf(ncf[r0+0][q], m3[q], fmaf(ncf[r0+1][q], m2[q], d[q]));
                    float t1 = fmaf(ncf[r0+2][q], m1[q], fmaf(ncf[r0+3][q], q1[q], t0));
                    d[q]    = fmaf(ncf[r0+4][q], q2[q], fmaf(ncf[r0+5][q], q3[q], t1));
                }
            }
            {   // stage 3 (s=64,128): lanes -16(M), +-32(C), +16(P)
                __builtin_amdgcn_wave_barrier();
                f4 pk; pk[0] = d[0]; pk[1] = d[1]; pk[2] = d[2]; pk[3] = d[3];
                scr[wv][L] = pk;
                __builtin_amdgcn_wave_barrier();
                f4 vM = scr[wv][(L + 48) & 63];
                f4 vC = scr[wv][(L + 32) & 63];
                f4 vP = scr[wv][(L + 16) & 63];
                __builtin_amdgcn_wave_barrier();
#pragma unroll
                for (int q = 0; q < 4; q++)
                    d[q] = fmaf(ncf[18][q], vM[q], fmaf(ncf[19][q], vC[q], fmaf(ncf[20][q], vP[q], d[q])));
            }
#pragma unroll
            for (int q = 0; q < 4; q++) d[q] *= ivd4[q];
            if (!isIC) {   // periodic Woodbury rank-2 correction (VALU readlane)
                float s1 = __builtin_bit_cast(float,
                    __builtin_amdgcn_readlane(__builtin_bit_cast(int, d[2]), 63));  // w[254]
                float s2 = __builtin_bit_cast(float,
                    __builtin_amdgcn_readlane(__builtin_bit_cast(int, d[1]), 0));   // w[1]
#pragma unroll
                for (int q = 0; q < 4; q++)
                    d[q] = fmaf(npk0[q], s1, fmaf(npk1[q], s2, d[q]));
            }
#pragma unroll
            for (int q = 0; q < 4; q++) y[q] = d[q];
            // ---- publish ----
            {
                f4 pk; pk[0] = y[0]; pk[1] = y[1]; pk[2] = y[2]; pk[3] = y[3];
                ring[t & 3][pubP][L] = pk;
            }
            if (pubDW) {
                f4 pk; pk[0] = dwv[0]; pk[1] = dwv[1]; pk[2] = dwv[2]; pk[3] = dwv[3];
                ring[t & 3][2][L] = pk;
            }
            if (needW && t <= 198) {
#pragma unroll
                for (int q = 0; q < 4; q++) { wprev[q] = wcur[q]; wcur[q] = wnxt[q]; }
            }
        }
        // ---- writer duty (lag 2): read 4 planes, transpose, float4 stores ----
        if (wgrp >= 0 && j >= 3) {
            const int tw = j - 2;
            const int s = tw & 3;
            f4 p0 = ring[s][wpl0][L];
            f4 p1 = ring[s][wpl1][L];
            f4 p2 = ring[s][wpl2][L];
            f4 p3 = ring[s][wpl3][L];
            f4* of4 = (f4*)out;
            size_t rb = ((size_t)b * 200 + tw) * 768;
#pragma unroll
            for (int q = 0; q < 4; q++) {
                f4 v; v[0] = p0[q]; v[1] = p1[q]; v[2] = p2[q]; v[3] = p3[q];
                of4[rb + (size_t)(4 * L + q) * 3 + wgrp] = v;
            }
        }
        lds_barrier();   // LDS-only: no vmcnt(0) drain of writer stores
    }
}

// ===================== launch =====================
extern "C" void kernel_launch(void* const* d_in, const int* in_sizes, int n_in,
                              void* d_out, int out_size, void* d_ws, size_t ws_size,
                              hipStream_t stream) {
    const float* W = (const float*)d_in[0];
    const float* U0 = (const float*)d_in[1];
    float* out = (float*)d_out;
    float* C = (float*)d_ws;   // 46*256 floats = 47 KB

    k_pcr<<<1, 256, 0, stream>>>(C);
    k_split<<<dim3(256), 448, 0, stream>>>(W, U0, C, out);
}

// Round 12
// 273.090 us; speedup vs baseline: 1.5206x; 1.0307x over previous
//
#include <hip/hip_runtime.h>

#define IDTF 199.0f
#define DTF  (1.0f/199.0f)

typedef float f4 __attribute__((ext_vector_type(4)));

// LDS-only barrier: orders DS ops across the workgroup without draining the
// global (vmcnt) queue.
__device__ __forceinline__ void lds_barrier() {
    asm volatile("s_waitcnt lgkmcnt(0)\n\ts_barrier" ::: "memory");
}

// ===================== PCR coefficient precompute (fp64) =====================
// (unchanged from round 9)
__global__ void k_pcr(float* __restrict__ C) {
    const double cc = 65025.0 / 199.0;   // eps*dt/dx^2 = 255^2/199
    __shared__ double a[2][256], b[2][256], c[2][256];
    __shared__ double AL[8][256], BE[8][256];
    const int x = threadIdx.x;
    double invd = 1.0;
    for (int mm = 0; mm < 2; mm++) {
        const int m = 1 - mm;
        double ai, bi, ci;
        if (m == 0) {
            ai = (x == 0) ? 0.0 : -cc;
            bi = 1.0 + 2.0 * cc;
            ci = (x == 255) ? 0.0 : -cc;
        } else {
            if (x == 0 || x == 255) { ai = 0.0; bi = 1.0; ci = 0.0; }
            else {
                ai = (x == 1) ? 0.0 : -cc;
                bi = 1.0 + 2.0 * cc;
                ci = (x == 254) ? 0.0 : -cc;
            }
        }
        int cur = 0;
        a[0][x] = ai; b[0][x] = bi; c[0][x] = ci;
        __syncthreads();
        for (int l = 0; l < 8; l++) {
            int s = 1 << l;
            int xm = (x - s < 0) ? 0 : x - s;
            int xp = (x + s > 255) ? 255 : x + s;
            double al = a[cur][x] / b[cur][xm];
            double be = c[cur][x] / b[cur][xp];
            AL[l][x] = al; BE[l][x] = be;
            double an = -al * a[cur][xm];
            double cn = -be * c[cur][xp];
            double bn = b[cur][x] - al * c[cur][xm] - be * a[cur][xp];
            a[1 - cur][x] = an; b[1 - cur][x] = bn; c[1 - cur][x] = cn;
            __syncthreads();
            cur ^= 1;
        }
        invd = 1.0 / b[cur][x];
        __syncthreads();
        float* Cr = C + (size_t)m * 22 * 256;
#pragma unroll
        for (int p = 0; p < 4; p++) {
            int s = 1 << (2 * p), s2 = 2 * s;
            double a0 = AL[2*p][x],   b0 = BE[2*p][x];
            double a1 = AL[2*p+1][x], b1 = BE[2*p+1][x];
            double am = (x - s2 >= 0) ? AL[2*p][x - s2] : 0.0;
            double bm = (x - s2 >= 0) ? BE[2*p][x - s2] : 0.0;
            double ap = (x + s2 < 256) ? AL[2*p][x + s2] : 0.0;
            double bq = (x + s2 < 256) ? BE[2*p][x + s2] : 0.0;
            double A3 = -a1 * am;
            double A2 = a1;
            double A1 = a0 - a1 * bm;
            double B1 = b0 - b1 * ap;
            double B2 = b1;
            double B3 = -b1 * bq;
            if (p < 3) {
                Cr[(p*6+0)*256 + x] = (float)A3;
                Cr[(p*6+1)*256 + x] = (float)A2;
                Cr[(p*6+2)*256 + x] = (float)A1;
                Cr[(p*6+3)*256 + x] = (float)B1;
                Cr[(p*6+4)*256 + x] = (float)B2;
                Cr[(p*6+5)*256 + x] = (float)B3;
            } else {
                Cr[18*256 + x] = (float)(A1 + B3);
                Cr[19*256 + x] = (float)(A2 + B2);
                Cr[20*256 + x] = (float)(A3 + B1);
            }
        }
        Cr[21*256 + x] = (float)invd;
        __syncthreads();
    }
    {
        int cur = 0;
        a[0][x] = (x == 0) ? -cc : 0.0;
        b[0][x] = (x == 255) ? -cc : 0.0;
        __syncthreads();
        for (int l = 0; l < 8; l++) {
            int s = 1 << l;
            int xm = (x - s < 0) ? 0 : x - s;
            int xp = (x + s > 255) ? 255 : x + s;
            double n1 = a[cur][x] - AL[l][x] * a[cur][xm] - BE[l][x] * a[cur][xp];
            double n2 = b[cur][x] - AL[l][x] * b[cur][xm] - BE[l][x] * b[cur][xp];
            a[1 - cur][x] = n1; b[1 - cur][x] = n2;
            __syncthreads();
            cur ^= 1;
        }
        double t1 = a[cur][x] * invd;
        double t2 = b[cur][x] * invd;
        c[0][x] = t1; c[1][x] = t2;
        __syncthreads();
        double K00 = 1.0 + c[0][254], K01 = c[1][254];
        double K10 = c[0][1],         K11 = 1.0 + c[1][1];
        double idet = 1.0 / (K00 * K11 - K01 * K10);
        double Ki00 = K11 * idet, Ki01 = -K01 * idet;
        double Ki10 = -K10 * idet, Ki11 = K00 * idet;
        C[44 * 256 + x] = (float)(t1 * Ki00 + t2 * Ki10);
        C[45 * 256 + x] = (float)(t1 * Ki01 + t2 * Ki11);
    }
}

// ===================== split scan kernel (superstep S=2) ====================
// grid(256) = 128 batches x 2 roles (paired 8 apart -> same XCD).
// 448 threads = 7 waves; lane L owns x = 4L..4L+3.
// role0 waves: {ic, f2, f4*, n8, n9, n10, n11}; writer wave n10 stores ch8-11.
// role1 waves: {ic*, f2*(+dW), n4, n3, n5, n6, n7}; writers n3 (ch0-3), n6
// (ch4-7). 8-slot LDS plane ring (slot = t&7); ONE barrier per 2 timesteps.
// Superstep s: producers t=2s+1,2s+2; consumers t=2s-1,2s (lag 2); writers
// burst tw=2s-3,2s-2 (lag 3-4). All read slots are >=1 barrier old and their
// overwrite is >=1 barrier away (window spans 6 of 8 slots).
__global__ __launch_bounds__(448, 1) void k_split(const float* __restrict__ W,
        const float* __restrict__ U0, const float* __restrict__ C,
        float* __restrict__ out) {
    const int bid = blockIdx.x;
    const int role = (bid >> 3) & 1;
    const int b = (bid & 7) | ((bid >> 4) << 3);
    const int tid = threadIdx.x;
    const int wv = tid >> 6;
    const int L = tid & 63;

    // config tables [role][wv]
    static const signed char FMT[2][7] = {{-1,-1,-1, 4, 1, 3, 2},
                                          {-1,-1,-1, 0, 1, 3, 2}};
    static const signed char PAT[2][7] = {{ 0, 0, 0, 1, 1, 0, 2},
                                          { 0, 0, 0, 0, 0, 1, 1}};
    static const signed char PBT[2][7] = {{ 0, 0, 0, 0, 0, 0, 1},
                                          { 0, 0, 0, 0, 0, 0, 0}};
    static const signed char PUBT[2][7]= {{ 0, 1, 2, 3, 4, 5, 6},
                                          { 0, 1, 3, 4, 5, 6, 7}};
    static const signed char NWT[2][7] = {{ 0, 1, 1, 0, 1, 0, 0},
                                          { 0, 1, 1, 0, 1, 0, 0}};
    static const signed char WGT[2][7] = {{-1,-1,-1,-1,-1, 2,-1},
                                          {-1,-1,-1, 0,-1, 1,-1}};
    static const signed char WPT[2][7][4] = {
        {{0,0,0,0},{0,0,0,0},{0,0,0,0},{0,0,0,0},{0,0,0,0},{3,4,5,6},{0,0,0,0}},
        {{0,0,0,0},{0,0,0,0},{0,0,0,0},{2,0,1,4},{0,0,0,0},{3,5,6,7},{0,0,0,0}}};

    const bool isIC = (wv == 0);
    const bool isProd = (wv < 3);
    const int pmode = wv;                 // producers: 0=ic, 1=dW, 2=dW^2
    const int fmode = FMT[role][wv];
    const int pAi = PAT[role][wv], pBi = PBT[role][wv];
    const int pubP = PUBT[role][wv];
    const bool needW = NWT[role][wv];
    const int wgrp = WGT[role][wv];
    const int wpl0 = WPT[role][wv][0], wpl1 = WPT[role][wv][1];
    const int wpl2 = WPT[role][wv][2], wpl3 = WPT[role][wv][3];
    const bool pubDW = (role == 1 && wv == 1);
    const int mat = isIC ? 1 : 0;

    // ---- fused-stage coefficients into registers (negated for fmaf) ----
    const float* Cm = C + (size_t)mat * 22 * 256;
    float ncf[21][4], ivd4[4], npk0[4], npk1[4];
#pragma unroll
    for (int r = 0; r < 21; r++) {
        f4 v = *(const f4*)&Cm[r * 256 + 4 * L];
#pragma unroll
        for (int q = 0; q < 4; q++) ncf[r][q] = -v[q];
    }
    {
        f4 vd = *(const f4*)&Cm[21 * 256 + 4 * L];
        f4 p0 = *(const f4*)&C[44 * 256 + 4 * L];
        f4 p1 = *(const f4*)&C[45 * 256 + 4 * L];
#pragma unroll
        for (int q = 0; q < 4; q++) { ivd4[q] = vd[q]; npk0[q] = -p0[q]; npk1[q] = -p1[q]; }
    }

    __shared__ f4 ring[8][8][64];   // 64 KB: [slot][plane][lane]
    __shared__ f4 scr[7][64];       // 7 KB per-wave PCR exchange

    // ---- state init ----
    float y[4] = {0.f, 0.f, 0.f, 0.f};
    if (isIC) {
        f4 u0 = *(const f4*)&U0[b * 256 + 4 * L];
#pragma unroll
        for (int q = 0; q < 4; q++) y[q] = u0[q];
    }
    // t=0 output row (writer waves; float4 stores)
    if (wgrp >= 0) {
        f4* of4 = (f4*)out;
        size_t rb = (size_t)b * 200 * 768;
#pragma unroll
        for (int q = 0; q < 4; q++) {
            int x = 4 * L + q;
            f4 v = {0.f, 0.f, 0.f, 0.f};
            if (wgrp == 0) v[1] = U0[b * 256 + x];
            of4[rb + (size_t)x * 3 + wgrp] = v;
        }
    }
    float wprev[4] = {0,0,0,0}, wcur[4] = {0,0,0,0}, wnxt[4] = {0,0,0,0};
    if (needW) {
        f4 w0 = *(const f4*)&W[((size_t)b * 200 + 0) * 256 + 4 * L];
        f4 w1 = *(const f4*)&W[((size_t)b * 200 + 1) * 256 + 4 * L];
#pragma unroll
        for (int q = 0; q < 4; q++) { wprev[q] = w0[q]; wcur[q] = w1[q]; }
    }
    __syncthreads();

    for (int s = 0; s <= 101; s++) {
#pragma unroll
        for (int k = 1; k <= 2; k++) {
            const int j = 2 * s + k;
            const int t = isProd ? j : (j - 2);
            const bool active = isProd ? (j <= 199) : (j >= 3 && j <= 201);
            if (active) {
                float dwv[4] = {0,0,0,0};
                if (needW) {
#pragma unroll
                    for (int q = 0; q < 4; q++) dwv[q] = (wcur[q] - wprev[q]) * IDTF;
                    if (t <= 198) {
                        f4 wn = *(const f4*)&W[((size_t)b * 200 + t + 1) * 256 + 4 * L];
#pragma unroll
                        for (int q = 0; q < 4; q++) wnxt[q] = wn[q];
                    }
                }
                // ---- forcing ----
                float d[4];
                if (isProd) {
                    if (pmode == 0) {
#pragma unroll
                        for (int q = 0; q < 4; q++) d[q] = y[q];
                    } else if (pmode == 1) {
#pragma unroll
                        for (int q = 0; q < 4; q++) d[q] = fmaf(dwv[q], DTF, y[q]);
                    } else {
#pragma unroll
                        for (int q = 0; q < 4; q++) d[q] = fmaf(dwv[q] * dwv[q], DTF, y[q]);
                    }
                } else {
                    f4 pa = ring[t & 7][pAi][L];
                    f4 pb = (fmode == 2) ? ring[t & 7][pBi][L] : pa;
#pragma unroll
                    for (int q = 0; q < 4; q++) {
                        float fq;
                        if (fmode == 0)      fq = pa[q];
                        else if (fmode == 1) fq = dwv[q] * pa[q];
                        else if (fmode == 2) fq = pb[q] * pa[q];
                        else if (fmode == 3) fq = pa[q] * pa[q];
                        else                 fq = pa[q] * pa[q] * pa[q];
                        d[q] = fmaf(fq, DTF, y[q]);
                    }
                }
                // ---- PCR solve: 4 fused stages, per-wave LDS b128 exchanges ----
                {   // stage 0 (s=1,2): lanes +-1, 12-elem window
                    __builtin_amdgcn_wave_barrier();
                    f4 pk; pk[0] = d[0]; pk[1] = d[1]; pk[2] = d[2]; pk[3] = d[3];
                    scr[wv][L] = pk;
                    __builtin_amdgcn_wave_barrier();
                    f4 vm = scr[wv][(L + 63) & 63];
                    f4 vp = scr[wv][(L + 1) & 63];
                    __builtin_amdgcn_wave_barrier();
                    float w[12], r[4];
                    w[0]=vm[0]; w[1]=vm[1]; w[2]=vm[2]; w[3]=vm[3];
                    w[4]=d[0];  w[5]=d[1];  w[6]=d[2];  w[7]=d[3];
                    w[8]=vp[0]; w[9]=vp[1]; w[10]=vp[2]; w[11]=vp[3];
#pragma unroll
                    for (int q = 0; q < 4; q++) {
                        float t0 = fmaf(ncf[0][q], w[q + 1], fmaf(ncf[1][q], w[q + 2], w[4 + q]));
                        float t1 = fmaf(ncf[2][q], w[q + 3], fmaf(ncf[3][q], w[q + 5], t0));
                        r[q] = fmaf(ncf[4][q], w[q + 6], fmaf(ncf[5][q], w[q + 7], t1));
                    }
                    d[0] = r[0]; d[1] = r[1]; d[2] = r[2]; d[3] = r[3];
                }
#pragma unroll
                for (int st = 1; st < 3; st++) {   // stage1: s=4; stage2: s=16
                    const int u = (st == 1) ? 1 : 4;
                    __builtin_amdgcn_wave_barrier();
                    f4 pk; pk[0] = d[0]; pk[1] = d[1]; pk[2] = d[2]; pk[3] = d[3];
                    scr[wv][L] = pk;
                    __builtin_amdgcn_wave_barrier();
                    f4 m1 = scr[wv][(L - u) & 63];
                    f4 m2 = scr[wv][(L - 2 * u) & 63];
                    f4 m3 = scr[wv][(L - 3 * u) & 63];
                    f4 q1 = scr[wv][(L + u) & 63];
                    f4 q2 = scr[wv][(L + 2 * u) & 63];
                    f4 q3 = scr[wv][(L + 3 * u) & 63];
                    __builtin_amdgcn_wave_barrier();
                    const int r0 = st * 6;
#pragma unroll
                    for (int q = 0; q < 4; q++) {
                        float t0 = fmaf(ncf[r0+0][q], m3[q], fmaf(ncf[r0+1][q], m2[q], d[q]));
                        float t1 = fmaf(ncf[r0+2][q], m1[q], fmaf(ncf[r0+3][q], q1[q], t0));
                        d[q]    = fmaf(ncf[r0+4][q], q2[q], fmaf(ncf[r0+5][q], q3[q], t1));
                    }
                }
                {   // stage 3 (s=64,128): lanes -16(M), +-32(C), +16(P)
                    __builtin_amdgcn_wave_barrier();
                    f4 pk; pk[0] = d[0]; pk[1] = d[1]; pk[2] = d[2]; pk[3] = d[3];
                    scr[wv][L] = pk;
                    __builtin_amdgcn_wave_barrier();
                    f4 vM = scr[wv][(L + 48) & 63];
                    f4 vC = scr[wv][(L + 32) & 63];
                    f4 vP = scr[wv][(L + 16) & 63];
                    __builtin_amdgcn_wave_barrier();
#pragma unroll
                    for (int q = 0; q < 4; q++)
                        d[q] = fmaf(ncf[18][q], vM[q], fmaf(ncf[19][q], vC[q], fmaf(ncf[20][q], vP[q], d[q])));
                }
#pragma unroll
                for (int q = 0; q < 4; q++) d[q] *= ivd4[q];
                if (!isIC) {   // periodic Woodbury rank-2 correction (VALU readlane)
                    float s1 = __builtin_bit_cast(float,
                        __builtin_amdgcn_readlane(__builtin_bit_cast(int, d[2]), 63));  // w[254]
                    float s2 = __builtin_bit_cast(float,
                        __builtin_amdgcn_readlane(__builtin_bit_cast(int, d[1]), 0));   // w[1]
#pragma unroll
                    for (int q = 0; q < 4; q++)
                        d[q] = fmaf(npk0[q], s1, fmaf(npk1[q], s2, d[q]));
                }
#pragma unroll
                for (int q = 0; q < 4; q++) y[q] = d[q];
                // ---- publish ----
                {
                    f4 pk; pk[0] = y[0]; pk[1] = y[1]; pk[2] = y[2]; pk[3] = y[3];
                    ring[t & 7][pubP][L] = pk;
                }
                if (pubDW) {
                    f4 pk; pk[0] = dwv[0]; pk[1] = dwv[1]; pk[2] = dwv[2]; pk[3] = dwv[3];
                    ring[t & 7][2][L] = pk;
                }
                if (needW && t <= 198) {
#pragma unroll
                    for (int q = 0; q < 4; q++) { wprev[q] = wcur[q]; wcur[q] = wnxt[q]; }
                }
            }
        }
        // ---- writer burst (lag 3-4): two timesteps from previous superstep ----
        if (wgrp >= 0) {
#pragma unroll
            for (int k = 0; k < 2; k++) {
                const int tw = 2 * s - 3 + k;
                if (tw >= 1 && tw <= 199) {
                    const int sl = tw & 7;
                    f4 p0 = ring[sl][wpl0][L];
                    f4 p1 = ring[sl][wpl1][L];
                    f4 p2 = ring[sl][wpl2][L];
                    f4 p3 = ring[sl][wpl3][L];
                    f4* of4 = (f4*)out;
                    size_t rb = ((size_t)b * 200 + tw) * 768;
#pragma unroll
                    for (int q = 0; q < 4; q++) {
                        f4 v; v[0] = p0[q]; v[1] = p1[q]; v[2] = p2[q]; v[3] = p3[q];
                        of4[rb + (size_t)(4 * L + q) * 3 + wgrp] = v;
                    }
                }
            }
        }
        lds_barrier();
    }
}

// ===================== launch =====================
extern "C" void kernel_launch(void* const* d_in, const int* in_sizes, int n_in,
                              void* d_out, int out_size, void* d_ws, size_t ws_size,
                              hipStream_t stream) {
    const float* W = (const float*)d_in[0];
    const float* U0 = (const float*)d_in[1];
    float* out = (float*)d_out;
    float* C = (float*)d_ws;   // 46*256 floats = 47 KB

    k_pcr<<<1, 256, 0, stream>>>(C);
    k_split<<<dim3(256), 448, 0, stream>>>(W, U0, C, out);
}

// Round 13
// 264.292 us; speedup vs baseline: 1.5712x; 1.0333x over previous
//
#include <hip/hip_runtime.h>

#define IDTF 199.0f
#define DTF  (1.0f/199.0f)
#define RING 12

typedef float f4 __attribute__((ext_vector_type(4)));

// LDS-only barrier: orders DS ops across the workgroup without draining the
// global (vmcnt) queue.
__device__ __forceinline__ void lds_barrier() {
    asm volatile("s_waitcnt lgkmcnt(0)\n\ts_barrier" ::: "memory");
}

// ===================== PCR coefficient precompute (fp64) =====================
// (unchanged from round 9)
__global__ void k_pcr(float* __restrict__ C) {
    const double cc = 65025.0 / 199.0;   // eps*dt/dx^2 = 255^2/199
    __shared__ double a[2][256], b[2][256], c[2][256];
    __shared__ double AL[8][256], BE[8][256];
    const int x = threadIdx.x;
    double invd = 1.0;
    for (int mm = 0; mm < 2; mm++) {
        const int m = 1 - mm;
        double ai, bi, ci;
        if (m == 0) {
            ai = (x == 0) ? 0.0 : -cc;
            bi = 1.0 + 2.0 * cc;
            ci = (x == 255) ? 0.0 : -cc;
        } else {
            if (x == 0 || x == 255) { ai = 0.0; bi = 1.0; ci = 0.0; }
            else {
                ai = (x == 1) ? 0.0 : -cc;
                bi = 1.0 + 2.0 * cc;
                ci = (x == 254) ? 0.0 : -cc;
            }
        }
        int cur = 0;
        a[0][x] = ai; b[0][x] = bi; c[0][x] = ci;
        __syncthreads();
        for (int l = 0; l < 8; l++) {
            int s = 1 << l;
            int xm = (x - s < 0) ? 0 : x - s;
            int xp = (x + s > 255) ? 255 : x + s;
            double al = a[cur][x] / b[cur][xm];
            double be = c[cur][x] / b[cur][xp];
            AL[l][x] = al; BE[l][x] = be;
            double an = -al * a[cur][xm];
            double cn = -be * c[cur][xp];
            double bn = b[cur][x] - al * c[cur][xm] - be * a[cur][xp];
            a[1 - cur][x] = an; b[1 - cur][x] = bn; c[1 - cur][x] = cn;
            __syncthreads();
            cur ^= 1;
        }
        invd = 1.0 / b[cur][x];
        __syncthreads();
        float* Cr = C + (size_t)m * 22 * 256;
#pragma unroll
        for (int p = 0; p < 4; p++) {
            int s = 1 << (2 * p), s2 = 2 * s;
            double a0 = AL[2*p][x],   b0 = BE[2*p][x];
            double a1 = AL[2*p+1][x], b1 = BE[2*p+1][x];
            double am = (x - s2 >= 0) ? AL[2*p][x - s2] : 0.0;
            double bm = (x - s2 >= 0) ? BE[2*p][x - s2] : 0.0;
            double ap = (x + s2 < 256) ? AL[2*p][x + s2] : 0.0;
            double bq = (x + s2 < 256) ? BE[2*p][x + s2] : 0.0;
            double A3 = -a1 * am;
            double A2 = a1;
            double A1 = a0 - a1 * bm;
            double B1 = b0 - b1 * ap;
            double B2 = b1;
            double B3 = -b1 * bq;
            if (p < 3) {
                Cr[(p*6+0)*256 + x] = (float)A3;
                Cr[(p*6+1)*256 + x] = (float)A2;
                Cr[(p*6+2)*256 + x] = (float)A1;
                Cr[(p*6+3)*256 + x] = (float)B1;
                Cr[(p*6+4)*256 + x] = (float)B2;
                Cr[(p*6+5)*256 + x] = (float)B3;
            } else {
                Cr[18*256 + x] = (float)(A1 + B3);
                Cr[19*256 + x] = (float)(A2 + B2);
                Cr[20*256 + x] = (float)(A3 + B1);
            }
        }
        Cr[21*256 + x] = (float)invd;
        __syncthreads();
    }
    {
        int cur = 0;
        a[0][x] = (x == 0) ? -cc : 0.0;
        b[0][x] = (x == 255) ? -cc : 0.0;
        __syncthreads();
        for (int l = 0; l < 8; l++) {
            int s = 1 << l;
            int xm = (x - s < 0) ? 0 : x - s;
            int xp = (x + s > 255) ? 255 : x + s;
            double n1 = a[cur][x] - AL[l][x] * a[cur][xm] - BE[l][x] * a[cur][xp];
            double n2 = b[cur][x] - AL[l][x] * b[cur][xm] - BE[l][x] * b[cur][xp];
            a[1 - cur][x] = n1; b[1 - cur][x] = n2;
            __syncthreads();
            cur ^= 1;
        }
        double t1 = a[cur][x] * invd;
        double t2 = b[cur][x] * invd;
        c[0][x] = t1; c[1][x] = t2;
        __syncthreads();
        double K00 = 1.0 + c[0][254], K01 = c[1][254];
        double K10 = c[0][1],         K11 = 1.0 + c[1][1];
        double idet = 1.0 / (K00 * K11 - K01 * K10);
        double Ki00 = K11 * idet, Ki01 = -K01 * idet;
        double Ki10 = -K10 * idet, Ki11 = K00 * idet;
        C[44 * 256 + x] = (float)(t1 * Ki00 + t2 * Ki10);
        C[45 * 256 + x] = (float)(t1 * Ki01 + t2 * Ki11);
    }
}

// ===================== split scan kernel (8 waves, superstep S=4) ===========
// grid(256) = 128 batches x 2 roles (paired 8 apart -> same XCD).
// 512 threads = 8 waves (2/SIMD, balanced); lane L owns x = 4L..4L+3.
// Waves 0-6: scans; wave 7: DEDICATED writer (no scan).
// role0 scans: {ic, f2, f4, n8, n9, n10, n11}; writer stores ch8-11.
// role1 scans: {ic, f2(+dW), n4, n3, n5, n6, n7}; writer stores ch0-3, ch4-7.
// 12-slot LDS plane ring; ONE barrier per 4 timesteps. Superstep s:
// producers t=4s+1..4s+4; consumers t=j-4 (lag 4); writer burst tw=4s-7..4s-4.
// Span 11 < 12; every cross-wave read >=1 barrier old, overwrite >=1 away.
__global__ __launch_bounds__(512, 1) void k_split(const float* __restrict__ W,
        const float* __restrict__ U0, const float* __restrict__ C,
        float* __restrict__ out) {
    const int bid = blockIdx.x;
    const int role = (bid >> 3) & 1;
    const int b = (bid & 7) | ((bid >> 4) << 3);
    const int tid = threadIdx.x;
    const int wv = tid >> 6;
    const int L = tid & 63;

    // TY: 0=ic-prod, 1=dW-prod(f2), 2=dW^2-prod(f4/n4), 3=consumer, 4=writer
    static const signed char TY[8]      = {0,1,2,3,3,3,3,4};
    static const signed char FMT[2][8]  = {{0,0,0,4,1,3,2,0},{0,0,0,0,1,3,2,0}};
    static const signed char PAT[2][8]  = {{0,0,0,1,1,0,2,0},{0,0,0,0,0,1,1,0}};
    static const signed char PBT[2][8]  = {{0,0,0,0,0,0,1,0},{0,0,0,0,0,0,0,0}};
    static const signed char PUB[2][8]  = {{0,1,2,3,4,5,6,0},{0,1,4,3,5,6,7,0}};
    static const signed char NW[8]      = {0,1,1,0,1,0,0,0};
    // writer plane groups: role0: 1 group (ch8-11); role1: 2 groups (ch0-3, ch4-7)
    static const signed char WGRP[2][2]    = {{2,-1},{0,1}};
    static const signed char WPL[2][2][4]  = {{{3,4,5,6},{0,0,0,0}},
                                              {{2,0,1,3},{4,5,6,7}}};

    const int  ty    = TY[wv];
    const bool isWr  = (ty == 4);
    const bool isIC  = (ty == 0);
    const bool isProd = (ty <= 2);
    const int  fmode = FMT[role][wv];
    const int  pAi = PAT[role][wv], pBi = PBT[role][wv];
    const int  pubP  = PUB[role][wv];
    const bool needW = NW[wv];
    const bool pubDW = (role == 1 && wv == 1);
    const int  mat   = isIC ? 1 : 0;

    // ---- fused-stage coefficients into registers (negated for fmaf) ----
    const float* Cm = C + (size_t)mat * 22 * 256;
    float ncf[21][4], ivd4[4], npk0[4], npk1[4];
#pragma unroll
    for (int r = 0; r < 21; r++) {
        f4 v = *(const f4*)&Cm[r * 256 + 4 * L];
#pragma unroll
        for (int q = 0; q < 4; q++) ncf[r][q] = -v[q];
    }
    {
        f4 vd = *(const f4*)&Cm[21 * 256 + 4 * L];
        f4 p0 = *(const f4*)&C[44 * 256 + 4 * L];
        f4 p1 = *(const f4*)&C[45 * 256 + 4 * L];
#pragma unroll
        for (int q = 0; q < 4; q++) { ivd4[q] = vd[q]; npk0[q] = -p0[q]; npk1[q] = -p1[q]; }
    }

    __shared__ f4 ring[RING][8][64];   // 96 KB: [slot][plane][lane]
    __shared__ f4 scr[8][64];          // 8 KB per-wave PCR exchange

    // ---- state init ----
    float y[4] = {0.f, 0.f, 0.f, 0.f};
    if (isIC) {
        f4 u0 = *(const f4*)&U0[b * 256 + 4 * L];
#pragma unroll
        for (int q = 0; q < 4; q++) y[q] = u0[q];
    }
    // t=0 output row (writer wave; float4 stores)
    if (isWr) {
        f4* of4 = (f4*)out;
        size_t rb = (size_t)b * 200 * 768;
#pragma unroll
        for (int g = 0; g < 2; g++) {
            const int wg = WGRP[role][g];
            if (wg < 0) continue;
#pragma unroll
            for (int q = 0; q < 4; q++) {
                int x = 4 * L + q;
                f4 v = {0.f, 0.f, 0.f, 0.f};
                if (wg == 0) v[1] = U0[b * 256 + x];
                of4[rb + (size_t)x * 3 + wg] = v;
            }
        }
    }
    float wprev[4] = {0,0,0,0}, wcur[4] = {0,0,0,0}, wnxt[4] = {0,0,0,0};
    if (needW) {
        f4 w0 = *(const f4*)&W[((size_t)b * 200 + 0) * 256 + 4 * L];
        f4 w1 = *(const f4*)&W[((size_t)b * 200 + 1) * 256 + 4 * L];
#pragma unroll
        for (int q = 0; q < 4; q++) { wprev[q] = w0[q]; wcur[q] = w1[q]; }
    }
    __syncthreads();

    int slot = 1;    // own-t ring slot (t starts at 1), wraps at RING
    int wslot = 1;   // writer's tw slot

    for (int s = 0; s <= 51; s++) {
        if (!isWr) {
            for (int k = 1; k <= 4; k++) {
                const int j = 4 * s + k;
                const int t = isProd ? j : (j - 4);
                const bool active = isProd ? (j <= 199) : (j >= 5 && j <= 203);
                if (!active) continue;
                float dwv[4] = {0,0,0,0};
                if (needW) {
#pragma unroll
                    for (int q = 0; q < 4; q++) dwv[q] = (wcur[q] - wprev[q]) * IDTF;
                    if (t <= 198) {
                        f4 wn = *(const f4*)&W[((size_t)b * 200 + t + 1) * 256 + 4 * L];
#pragma unroll
                        for (int q = 0; q < 4; q++) wnxt[q] = wn[q];
                    }
                }
                // ---- forcing ----
                float d[4];
                if (isProd) {
                    if (ty == 0) {
#pragma unroll
                        for (int q = 0; q < 4; q++) d[q] = y[q];
                    } else if (ty == 1) {
#pragma unroll
                        for (int q = 0; q < 4; q++) d[q] = fmaf(dwv[q], DTF, y[q]);
                    } else {
#pragma unroll
                        for (int q = 0; q < 4; q++) d[q] = fmaf(dwv[q] * dwv[q], DTF, y[q]);
                    }
                } else {
                    f4 pa = ring[slot][pAi][L];
                    f4 pb = (fmode == 2) ? ring[slot][pBi][L] : pa;
#pragma unroll
                    for (int q = 0; q < 4; q++) {
                        float fq;
                        if (fmode == 0)      fq = pa[q];
                        else if (fmode == 1) fq = dwv[q] * pa[q];
                        else if (fmode == 2) fq = pb[q] * pa[q];
                        else if (fmode == 3) fq = pa[q] * pa[q];
                        else                 fq = pa[q] * pa[q] * pa[q];
                        d[q] = fmaf(fq, DTF, y[q]);
                    }
                }
                // ---- PCR solve: 4 fused stages, per-wave LDS b128 exchanges ----
                {   // stage 0 (s=1,2): lanes +-1, 12-elem window
                    __builtin_amdgcn_wave_barrier();
                    f4 pk; pk[0] = d[0]; pk[1] = d[1]; pk[2] = d[2]; pk[3] = d[3];
                    scr[wv][L] = pk;
                    __builtin_amdgcn_wave_barrier();
                    f4 vm = scr[wv][(L + 63) & 63];
                    f4 vp = scr[wv][(L + 1) & 63];
                    __builtin_amdgcn_wave_barrier();
                    float w[12], r[4];
                    w[0]=vm[0]; w[1]=vm[1]; w[2]=vm[2]; w[3]=vm[3];
                    w[4]=d[0];  w[5]=d[1];  w[6]=d[2];  w[7]=d[3];
                    w[8]=vp[0]; w[9]=vp[1]; w[10]=vp[2]; w[11]=vp[3];
#pragma unroll
                    for (int q = 0; q < 4; q++) {
                        float t0 = fmaf(ncf[0][q], w[q + 1], fmaf(ncf[1][q], w[q + 2], w[4 + q]));
                        float t1 = fmaf(ncf[2][q], w[q + 3], fmaf(ncf[3][q], w[q + 5], t0));
                        r[q] = fmaf(ncf[4][q], w[q + 6], fmaf(ncf[5][q], w[q + 7], t1));
                    }
                    d[0] = r[0]; d[1] = r[1]; d[2] = r[2]; d[3] = r[3];
                }
#pragma unroll
                for (int st = 1; st < 3; st++) {   // stage1: s=4; stage2: s=16
                    const int u = (st == 1) ? 1 : 4;
                    __builtin_amdgcn_wave_barrier();
                    f4 pk; pk[0] = d[0]; pk[1] = d[1]; pk[2] = d[2]; pk[3] = d[3];
                    scr[wv][L] = pk;
                    __builtin_amdgcn_wave_barrier();
                    f4 m1 = scr[wv][(L - u) & 63];
                    f4 m2 = scr[wv][(L - 2 * u) & 63];
                    f4 m3 = scr[wv][(L - 3 * u) & 63];
                    f4 q1 = scr[wv][(L + u) & 63];
                    f4 q2 = scr[wv][(L + 2 * u) & 63];
                    f4 q3 = scr[wv][(L + 3 * u) & 63];
                    __builtin_amdgcn_wave_barrier();
                    const int r0 = st * 6;
#pragma unroll
                    for (int q = 0; q < 4; q++) {
                        float t0 = fmaf(ncf[r0+0][q], m3[q], fmaf(ncf[r0+1][q], m2[q], d[q]));
                        float t1 = fmaf(ncf[r0+2][q], m1[q], fmaf(ncf[r0+3][q], q1[q], t0));
                        d[q]    = fmaf(ncf[r0+4][q], q2[q], fmaf(ncf[r0+5][q], q3[q], t1));
                    }
                }
                {   // stage 3 (s=64,128): lanes -16(M), +-32(C), +16(P)
                    __builtin_amdgcn_wave_barrier();
                    f4 pk; pk[0] = d[0]; pk[1] = d[1]; pk[2] = d[2]; pk[3] = d[3];
                    scr[wv][L] = pk;
                    __builtin_amdgcn_wave_barrier();
                    f4 vM = scr[wv][(L + 48) & 63];
                    f4 vC = scr[wv][(L + 32) & 63];
                    f4 vP = scr[wv][(L + 16) & 63];
                    __builtin_amdgcn_wave_barrier();
#pragma unroll
                    for (int q = 0; q < 4; q++)
                        d[q] = fmaf(ncf[18][q], vM[q], fmaf(ncf[19][q], vC[q], fmaf(ncf[20][q], vP[q], d[q])));
                }
#pragma unroll
                for (int q = 0; q < 4; q++) d[q] *= ivd4[q];
                if (!isIC) {   // periodic Woodbury rank-2 correction (VALU readlane)
                    float s1 = __builtin_bit_cast(float,
                        __builtin_amdgcn_readlane(__builtin_bit_cast(int, d[2]), 63));  // w[254]
                    float s2 = __builtin_bit_cast(float,
                        __builtin_amdgcn_readlane(__builtin_bit_cast(int, d[1]), 0));   // w[1]
#pragma unroll
                    for (int q = 0; q < 4; q++)
                        d[q] = fmaf(npk0[q], s1, fmaf(npk1[q], s2, d[q]));
                }
#pragma unroll
                for (int q = 0; q < 4; q++) y[q] = d[q];
                // ---- publish ----
                {
                    f4 pk; pk[0] = y[0]; pk[1] = y[1]; pk[2] = y[2]; pk[3] = y[3];
                    ring[slot][pubP][L] = pk;
                }
                if (pubDW) {
                    f4 pk; pk[0] = dwv[0]; pk[1] = dwv[1]; pk[2] = dwv[2]; pk[3] = dwv[3];
                    ring[slot][2][L] = pk;
                }
                if (needW && t <= 198) {
#pragma unroll
                    for (int q = 0; q < 4; q++) { wprev[q] = wcur[q]; wcur[q] = wnxt[q]; }
                }
                slot = (slot == RING - 1) ? 0 : (slot + 1);
            }
        } else {
            // ---- writer burst (lag 5-8): 4 timesteps from older supersteps ----
            f4* of4 = (f4*)out;
#pragma unroll
            for (int k = 0; k < 4; k++) {
                const int tw = 4 * s - 7 + k;
                if (tw < 1 || tw > 199) continue;
                size_t rb = ((size_t)b * 200 + tw) * 768;
#pragma unroll
                for (int g = 0; g < 2; g++) {
                    const int wg = WGRP[role][g];
                    if (wg < 0) continue;
                    f4 p0 = ring[wslot][WPL[role][g][0]][L];
                    f4 p1 = ring[wslot][WPL[role][g][1]][L];
                    f4 p2 = ring[wslot][WPL[role][g][2]][L];
                    f4 p3 = ring[wslot][WPL[role][g][3]][L];
#pragma unroll
                    for (int q = 0; q < 4; q++) {
                        f4 v; v[0] = p0[q]; v[1] = p1[q]; v[2] = p2[q]; v[3] = p3[q];
                        of4[rb + (size_t)(4 * L + q) * 3 + wg] = v;
                    }
                }
                wslot = (wslot == RING - 1) ? 0 : (wslot + 1);
            }
        }
        lds_barrier();
    }
}

// ===================== launch =====================
extern "C" void kernel_launch(void* const* d_in, const int* in_sizes, int n_in,
                              void* d_out, int out_size, void* d_ws, size_t ws_size,
                              hipStream_t stream) {
    const float* W = (const float*)d_in[0];
    const float* U0 = (const float*)d_in[1];
    float* out = (float*)d_out;
    float* C = (float*)d_ws;   // 46*256 floats = 47 KB

    k_pcr<<<1, 256, 0, stream>>>(C);
    k_split<<<dim3(256), 512, 0, stream>>>(W, U0, C, out);
}

// Round 14
// 205.306 us; speedup vs baseline: 2.0226x; 1.2873x over previous
//
#include <hip/hip_runtime.h>

#define IDTF 199.0f
#define DTF  (1.0f/199.0f)
#define RING 12

typedef float f4 __attribute__((ext_vector_type(4)));

__device__ __forceinline__ void lds_barrier() {
    asm volatile("s_waitcnt lgkmcnt(0)\n\ts_barrier" ::: "memory");
}
__device__ __forceinline__ float bp(int idx, float v) {
    return __builtin_bit_cast(float,
        __builtin_amdgcn_ds_bpermute(idx, __builtin_bit_cast(int, v)));
}

// ===================== SPIKE + PCR coefficient precompute (fp64) ============
// B = I - c*A; m=0 truncated-periodic T (corners via Woodbury), m=1 Dirichlet.
// Lane L owns rows 4L..4L+3: interior 4L..4L+2, separator X_L = row 4L+3.
// C layout (floats), per m at m*2560 (rows of 64):
//   rows 0-8: Minv[i][j] (3x3 interior inverse); 9-11: alpha_i; 12-14: beta_i;
//   15: a_s; 16: c_s; 17-34: fused PCR-64 stage coeffs (3 stages x A3,A2,A1,
//   B1,B2,B3); 35: invdX.  Woodbury PK columns (256-wide): C[5120+x], C[5376+x].
__global__ void k_pcr(float* __restrict__ C) {
    const double cc = 65025.0 / 199.0;   // eps*dt/dx^2 = 255^2/199
    __shared__ double pa[2][256], pb[2][256], pc[2][256];
    __shared__ double AL[8][256], BE[8][256];
    __shared__ double ca[256], cb[256], ccx[256];
    __shared__ double salp0[64], sbet0[64];
    __shared__ double Ah[64], Bh[64], Ch[64];
    __shared__ double AL6[6][64], BE6[6][64];
    const int x = threadIdx.x;

    // ---- Woodbury PK columns (m=0, full 256 fp64 PCR) ----
    {
        double ai = (x == 0) ? 0.0 : -cc;
        double bi = 1.0 + 2.0 * cc;
        double ci = (x == 255) ? 0.0 : -cc;
        int cur = 0;
        pa[0][x] = ai; pb[0][x] = bi; pc[0][x] = ci;
        __syncthreads();
        for (int l = 0; l < 8; l++) {
            int s = 1 << l, xm = (x - s < 0) ? 0 : x - s, xp = (x + s > 255) ? 255 : x + s;
            double al = pa[cur][x] / pb[cur][xm];
            double be = pc[cur][x] / pb[cur][xp];
            AL[l][x] = al; BE[l][x] = be;
            double an = -al * pa[cur][xm];
            double cn = -be * pc[cur][xp];
            double bn = pb[cur][x] - al * pc[cur][xm] - be * pa[cur][xp];
            pa[1 - cur][x] = an; pb[1 - cur][x] = bn; pc[1 - cur][x] = cn;
            __syncthreads();
            cur ^= 1;
        }
        double invd = 1.0 / pb[cur][x];
        __syncthreads();
        int cw = 0;
        pa[0][x] = (x == 0) ? -cc : 0.0;     // r1 = -c e0
        pc[0][x] = (x == 255) ? -cc : 0.0;   // r2 = -c e255
        __syncthreads();
        for (int l = 0; l < 8; l++) {
            int s = 1 << l, xm = (x - s < 0) ? 0 : x - s, xp = (x + s > 255) ? 255 : x + s;
            double n1 = pa[cw][x] - AL[l][x] * pa[cw][xm] - BE[l][x] * pa[cw][xp];
            double n2 = pc[cw][x] - AL[l][x] * pc[cw][xm] - BE[l][x] * pc[cw][xp];
            pa[1 - cw][x] = n1; pc[1 - cw][x] = n2;
            __syncthreads();
            cw ^= 1;
        }
        double t1 = pa[cw][x] * invd, t2 = pc[cw][x] * invd;
        pa[1 - cw][x] = t1; pc[1 - cw][x] = t2;
        __syncthreads();
        double K00 = 1.0 + pa[1 - cw][254], K01 = pc[1 - cw][254];
        double K10 = pa[1 - cw][1],         K11 = 1.0 + pc[1 - cw][1];
        double idet = 1.0 / (K00 * K11 - K01 * K10);
        C[5120 + x] = (float)(t1 * (K11 * idet) + t2 * (-K10 * idet));
        C[5376 + x] = (float)(t1 * (-K01 * idet) + t2 * (K00 * idet));
        __syncthreads();
    }
    // ---- SPIKE coefficients per variant ----
    for (int m = 0; m < 2; m++) {
        double ai, bi, ci;
        if (m == 0) {
            ai = (x == 0) ? 0.0 : -cc;
            bi = 1.0 + 2.0 * cc;
            ci = (x == 255) ? 0.0 : -cc;
        } else {
            if (x == 0 || x == 255) { ai = 0.0; bi = 1.0; ci = 0.0; }
            else {
                ai = (x == 1) ? 0.0 : -cc;
                bi = 1.0 + 2.0 * cc;
                ci = (x == 254) ? 0.0 : -cc;
            }
        }
        ca[x] = ai; cb[x] = bi; ccx[x] = ci;
        __syncthreads();
        float* Cr = C + m * 2560;
        double as_ = 0, cs_ = 0, bs_ = 0, alp2 = 0, bet2 = 0;
        if (x < 64) {
            int r0 = 4 * x;
            double m00 = cb[r0],     m01 = ccx[r0];
            double m10 = ca[r0 + 1], m11 = cb[r0 + 1], m12 = ccx[r0 + 1];
            double m21 = ca[r0 + 2], m22 = cb[r0 + 2];
            double C00 = m11 * m22 - m12 * m21, C01 = -m10 * m22, C02 = m10 * m21;
            double C10 = -m01 * m22, C11 = m00 * m22, C12 = -m00 * m21;
            double C20 = m01 * m12, C21 = -m00 * m12, C22 = m00 * m11 - m01 * m10;
            double det = m00 * C00 + m01 * C01;
            double id = 1.0 / det;
            double Mi[3][3] = {{C00 * id, C10 * id, C20 * id},
                               {C01 * id, C11 * id, C21 * id},
                               {C02 * id, C12 * id, C22 * id}};
            double aL = ca[r0], cR = ccx[r0 + 2];
            double alp[3], bet[3];
            for (int i = 0; i < 3; i++) { alp[i] = Mi[i][0] * aL; bet[i] = Mi[i][2] * cR; }
            salp0[x] = alp[0]; sbet0[x] = bet[0];
            as_ = ca[r0 + 3]; cs_ = ccx[r0 + 3]; bs_ = cb[r0 + 3];
            alp2 = alp[2]; bet2 = bet[2];
            for (int i = 0; i < 3; i++)
                for (int j = 0; j < 3; j++)
                    Cr[(i * 3 + j) * 64 + x] = (float)Mi[i][j];
            for (int i = 0; i < 3; i++) {
                Cr[(9 + i) * 64 + x] = (float)alp[i];
                Cr[(12 + i) * 64 + x] = (float)bet[i];
            }
            Cr[15 * 64 + x] = (float)as_;
            Cr[16 * 64 + x] = (float)cs_;
        }
        __syncthreads();
        if (x < 64) {
            int xp = (x + 1) & 63;
            double a0n = salp0[xp], b0n = sbet0[xp];   // garbage at x=63: cs_=0
            Ah[x] = -as_ * alp2;
            Bh[x] = bs_ - as_ * bet2 - cs_ * a0n;
            Ch[x] = -cs_ * b0n;
        }
        __syncthreads();
        // 6-level fp64 PCR on the 64-unknown reduced tridiagonal
        double bfin = 1.0;
        for (int l = 0; l < 6; l++) {
            int s = 1 << l;
            double an = 0, bn = 1, cn = 0;
            if (x < 64) {
                double Acur = Ah[x], Bcur = Bh[x], Ccur = Ch[x];
                double Am = (x - s >= 0) ? Ah[x - s] : 0.0;
                double Bm = (x - s >= 0) ? Bh[x - s] : 1.0;
                double Cm = (x - s >= 0) ? Ch[x - s] : 0.0;
                double Ap = (x + s < 64) ? Ah[x + s] : 0.0;
                double Bp = (x + s < 64) ? Bh[x + s] : 1.0;
                double Cp = (x + s < 64) ? Ch[x + s] : 0.0;
                double al = (x - s >= 0) ? Acur / Bm : 0.0;
                double be = (x + s < 64) ? Ccur / Bp : 0.0;
                AL6[l][x] = al; BE6[l][x] = be;
                an = -al * Am;
                cn = -be * Cp;
                bn = Bcur - al * Cm - be * Ap;
            }
            __syncthreads();
            if (x < 64) { Ah[x] = an; Bh[x] = bn; Ch[x] = cn; bfin = bn; }
            __syncthreads();
        }
        if (x < 64) {
            for (int p = 0; p < 3; p++) {
                int s2 = 2 * (1 << (2 * p));
                double a0 = AL6[2 * p][x],     b0 = BE6[2 * p][x];
                double a1 = AL6[2 * p + 1][x], b1 = BE6[2 * p + 1][x];
                double am = (x - s2 >= 0) ? AL6[2 * p][x - s2] : 0.0;
                double bm = (x - s2 >= 0) ? BE6[2 * p][x - s2] : 0.0;
                double ap = (x + s2 < 64) ? AL6[2 * p][x + s2] : 0.0;
                double bq = (x + s2 < 64) ? BE6[2 * p][x + s2] : 0.0;
                Cr[(17 + p * 6 + 0) * 64 + x] = (float)(-a1 * am);
                Cr[(17 + p * 6 + 1) * 64 + x] = (float)(a1);
                Cr[(17 + p * 6 + 2) * 64 + x] = (float)(a0 - a1 * bm);
                Cr[(17 + p * 6 + 3) * 64 + x] = (float)(b0 - b1 * ap);
                Cr[(17 + p * 6 + 4) * 64 + x] = (float)(b1);
                Cr[(17 + p * 6 + 5) * 64 + x] = (float)(-b1 * bq);
            }
            Cr[35 * 64 + x] = (float)(1.0 / bfin);
        }
        __syncthreads();
    }
}

// ===================== split scan kernel (SPIKE solve, 8 waves, S=4) ========
// Structure identical to round 13 (verified): grid(256)=128 batches x 2 roles
// (XCD-paired), 512 thr = 8 waves, 12-slot ring, barrier per 4 timesteps,
// dedicated writer wave. Solve replaced by SPIKE: interior 3x3 (registers) +
// 64-unknown PCR via ds_bpermute (no LDS scratch, no wave barriers).
__global__ __launch_bounds__(512, 1) void k_split(const float* __restrict__ W,
        const float* __restrict__ U0, const float* __restrict__ C,
        float* __restrict__ out) {
    const int bid = blockIdx.x;
    const int role = (bid >> 3) & 1;
    const int b = (bid & 7) | ((bid >> 4) << 3);
    const int tid = threadIdx.x;
    const int wv = tid >> 6;
    const int L = tid & 63;

    static const signed char TY[8]      = {0,1,2,3,3,3,3,4};
    static const signed char FMT[2][8]  = {{0,0,0,4,1,3,2,0},{0,0,0,0,1,3,2,0}};
    static const signed char PAT[2][8]  = {{0,0,0,1,1,0,2,0},{0,0,0,0,0,1,1,0}};
    static const signed char PBT[2][8]  = {{0,0,0,0,0,0,1,0},{0,0,0,0,0,0,0,0}};
    static const signed char PUB[2][8]  = {{0,1,2,3,4,5,6,0},{0,1,4,3,5,6,7,0}};
    static const signed char NW[8]      = {0,1,1,0,1,0,0,0};
    static const signed char WGRP[2][2]    = {{2,-1},{0,1}};
    static const signed char WPL[2][2][4]  = {{{3,4,5,6},{0,0,0,0}},
                                              {{2,0,1,3},{4,5,6,7}}};

    const int  ty    = TY[wv];
    const bool isWr  = (ty == 4);
    const bool isIC  = (ty == 0);
    const bool isProd = (ty <= 2);
    const int  fmode = FMT[role][wv];
    const int  pAi = PAT[role][wv], pBi = PBT[role][wv];
    const int  pubP  = PUB[role][wv];
    const bool needW = NW[wv];
    const bool pubDW = (role == 1 && wv == 1);
    const int  mat   = isIC ? 1 : 0;

    // ---- SPIKE coefficients into registers ----
    const float* Cr = C + mat * 2560;
    float fMi[9], nalp[3], nbet[3], nst[3][6];
#pragma unroll
    for (int k = 0; k < 9; k++) fMi[k] = Cr[k * 64 + L];
#pragma unroll
    for (int i = 0; i < 3; i++) {
        nalp[i] = -Cr[(9 + i) * 64 + L];
        nbet[i] = -Cr[(12 + i) * 64 + L];
    }
    const float nas = -Cr[15 * 64 + L];
    const float ncs = -Cr[16 * 64 + L];
#pragma unroll
    for (int p = 0; p < 3; p++)
#pragma unroll
        for (int k = 0; k < 6; k++) nst[p][k] = -Cr[(17 + p * 6 + k) * 64 + L];
    const float invdX = Cr[35 * 64 + L];
    float npk0[4], npk1[4];
    {
        f4 p0 = *(const f4*)&C[5120 + 4 * L];
        f4 p1 = *(const f4*)&C[5376 + 4 * L];
#pragma unroll
        for (int q = 0; q < 4; q++) { npk0[q] = -p0[q]; npk1[q] = -p1[q]; }
    }
    // bpermute lane indices
    int ixm[3][3], ixp[3][3];
#pragma unroll
    for (int p = 0; p < 3; p++) {
        const int sg = (p == 0) ? 1 : ((p == 1) ? 4 : 16);
#pragma unroll
        for (int k = 0; k < 3; k++) {
            ixm[p][k] = ((L - (k + 1) * sg) & 63) << 2;
            ixp[p][k] = ((L + (k + 1) * sg) & 63) << 2;
        }
    }

    __shared__ f4 ring[RING][8][64];   // 96 KB

    // ---- state init ----
    float y[4] = {0.f, 0.f, 0.f, 0.f};
    if (isIC) {
        f4 u0v = *(const f4*)&U0[b * 256 + 4 * L];
#pragma unroll
        for (int q = 0; q < 4; q++) y[q] = u0v[q];
    }
    if (isWr) {
        f4* of4 = (f4*)out;
        size_t rb = (size_t)b * 200 * 768;
#pragma unroll
        for (int g = 0; g < 2; g++) {
            const int wg = WGRP[role][g];
            if (wg < 0) continue;
#pragma unroll
            for (int q = 0; q < 4; q++) {
                int xx = 4 * L + q;
                f4 v = {0.f, 0.f, 0.f, 0.f};
                if (wg == 0) v[1] = U0[b * 256 + xx];
                of4[rb + (size_t)xx * 3 + wg] = v;
            }
        }
    }
    float wprev[4] = {0,0,0,0}, wcur[4] = {0,0,0,0}, wnxt[4] = {0,0,0,0};
    if (needW) {
        f4 w0 = *(const f4*)&W[((size_t)b * 200 + 0) * 256 + 4 * L];
        f4 w1 = *(const f4*)&W[((size_t)b * 200 + 1) * 256 + 4 * L];
#pragma unroll
        for (int q = 0; q < 4; q++) { wprev[q] = w0[q]; wcur[q] = w1[q]; }
    }
    __syncthreads();

    int slot = 1;    // own-t ring slot, wraps at RING
    int wslot = 1;   // writer's tw slot

    for (int s = 0; s <= 51; s++) {
        if (!isWr) {
            for (int k = 1; k <= 4; k++) {
                const int j = 4 * s + k;
                const int t = isProd ? j : (j - 4);
                const bool active = isProd ? (j <= 199) : (j >= 5 && j <= 203);
                if (!active) continue;
                float dwv[4] = {0,0,0,0};
                if (needW) {
#pragma unroll
                    for (int q = 0; q < 4; q++) dwv[q] = (wcur[q] - wprev[q]) * IDTF;
                    if (t <= 198) {
                        f4 wn = *(const f4*)&W[((size_t)b * 200 + t + 1) * 256 + 4 * L];
#pragma unroll
                        for (int q = 0; q < 4; q++) wnxt[q] = wn[q];
                    }
                }
                // ---- forcing ----
                float d[4];
                if (isProd) {
                    if (ty == 0) {
#pragma unroll
                        for (int q = 0; q < 4; q++) d[q] = y[q];
                    } else if (ty == 1) {
#pragma unroll
                        for (int q = 0; q < 4; q++) d[q] = fmaf(dwv[q], DTF, y[q]);
                    } else {
#pragma unroll
                        for (int q = 0; q < 4; q++) d[q] = fmaf(dwv[q] * dwv[q], DTF, y[q]);
                    }
                } else {
                    f4 pa = ring[slot][pAi][L];
                    f4 pb2 = (fmode == 2) ? ring[slot][pBi][L] : pa;
#pragma unroll
                    for (int q = 0; q < 4; q++) {
                        float fq;
                        if (fmode == 0)      fq = pa[q];
                        else if (fmode == 1) fq = dwv[q] * pa[q];
                        else if (fmode == 2) fq = pb2[q] * pa[q];
                        else if (fmode == 3) fq = pa[q] * pa[q];
                        else                 fq = pa[q] * pa[q] * pa[q];
                        d[q] = fmaf(fq, DTF, y[q]);
                    }
                }
                // ---- SPIKE solve: B d' = d ----
                float u0 = fmaf(fMi[2], d[2], fmaf(fMi[1], d[1], fMi[0] * d[0]));
                float u1 = fmaf(fMi[5], d[2], fmaf(fMi[4], d[1], fMi[3] * d[0]));
                float u2 = fmaf(fMi[8], d[2], fmaf(fMi[7], d[1], fMi[6] * d[0]));
                float X = fmaf(nas, u2, fmaf(ncs, bp(ixp[0][0], u0), d[3]));
#pragma unroll
                for (int p = 0; p < 3; p++) {
                    float m3 = bp(ixm[p][2], X), m2 = bp(ixm[p][1], X), m1 = bp(ixm[p][0], X);
                    float q1 = bp(ixp[p][0], X), q2 = bp(ixp[p][1], X), q3 = bp(ixp[p][2], X);
                    float t0 = fmaf(nst[p][0], m3, fmaf(nst[p][1], m2, X));
                    float t1 = fmaf(nst[p][2], m1, fmaf(nst[p][3], q1, t0));
                    X = fmaf(nst[p][4], q2, fmaf(nst[p][5], q3, t1));
                }
                X *= invdX;
                float Xm = bp(ixm[0][0], X);
                d[0] = fmaf(nalp[0], Xm, fmaf(nbet[0], X, u0));
                d[1] = fmaf(nalp[1], Xm, fmaf(nbet[1], X, u1));
                d[2] = fmaf(nalp[2], Xm, fmaf(nbet[2], X, u2));
                d[3] = X;
                if (!isIC) {   // periodic Woodbury rank-2 correction
                    float s1 = __builtin_bit_cast(float,
                        __builtin_amdgcn_readlane(__builtin_bit_cast(int, d[2]), 63));  // x=254
                    float s2 = __builtin_bit_cast(float,
                        __builtin_amdgcn_readlane(__builtin_bit_cast(int, d[1]), 0));   // x=1
#pragma unroll
                    for (int q = 0; q < 4; q++)
                        d[q] = fmaf(npk0[q], s1, fmaf(npk1[q], s2, d[q]));
                }
#pragma unroll
                for (int q = 0; q < 4; q++) y[q] = d[q];
                // ---- publish ----
                {
                    f4 pk; pk[0] = y[0]; pk[1] = y[1]; pk[2] = y[2]; pk[3] = y[3];
                    ring[slot][pubP][L] = pk;
                }
                if (pubDW) {
                    f4 pk; pk[0] = dwv[0]; pk[1] = dwv[1]; pk[2] = dwv[2]; pk[3] = dwv[3];
                    ring[slot][2][L] = pk;
                }
                if (needW && t <= 198) {
#pragma unroll
                    for (int q = 0; q < 4; q++) { wprev[q] = wcur[q]; wcur[q] = wnxt[q]; }
                }
                slot = (slot == RING - 1) ? 0 : (slot + 1);
            }
        } else {
            // ---- writer burst (lag 5-8) ----
            f4* of4 = (f4*)out;
#pragma unroll
            for (int k = 0; k < 4; k++) {
                const int tw = 4 * s - 7 + k;
                if (tw < 1 || tw > 199) continue;
                size_t rb = ((size_t)b * 200 + tw) * 768;
#pragma unroll
                for (int g = 0; g < 2; g++) {
                    const int wg = WGRP[role][g];
                    if (wg < 0) continue;
                    f4 p0 = ring[wslot][WPL[role][g][0]][L];
                    f4 p1 = ring[wslot][WPL[role][g][1]][L];
                    f4 p2 = ring[wslot][WPL[role][g][2]][L];
                    f4 p3 = ring[wslot][WPL[role][g][3]][L];
#pragma unroll
                    for (int q = 0; q < 4; q++) {
                        f4 v; v[0] = p0[q]; v[1] = p1[q]; v[2] = p2[q]; v[3] = p3[q];
                        of4[rb + (size_t)(4 * L + q) * 3 + wg] = v;
                    }
                }
                wslot = (wslot == RING - 1) ? 0 : (wslot + 1);
            }
        }
        lds_barrier();
    }
}

// ===================== launch =====================
extern "C" void kernel_launch(void* const* d_in, const int* in_sizes, int n_in,
                              void* d_out, int out_size, void* d_ws, size_t ws_size,
                              hipStream_t stream) {
    const float* W = (const float*)d_in[0];
    const float* U0 = (const float*)d_in[1];
    float* out = (float*)d_out;
    float* C = (float*)d_ws;   // ~5632 floats = 22.5 KB

    k_pcr<<<1, 256, 0, stream>>>(C);
    k_split<<<dim3(256), 512, 0, stream>>>(W, U0, C, out);
}